// Round 3
// baseline (1648.829 us; speedup 1.0000x reference)
//
#include <hip/hip_runtime.h>

// ---------- bf16 helpers (raw ushort representation) ----------
__device__ __forceinline__ float b2f(ushort u) {
    union { float f; unsigned int i; } w; w.i = ((unsigned int)u) << 16; return w.f;
}
__device__ __forceinline__ ushort f2b(float f) {
    union { float f; unsigned int i; } w; w.f = f;
    unsigned int lsb = (w.i >> 16) & 1u;
    w.i += 0x7fffu + lsb;
    return (ushort)(w.i >> 16);
}

typedef __bf16 bf16x8 __attribute__((ext_vector_type(8)));
typedef float floatx4 __attribute__((ext_vector_type(4)));

// Problem constants
#define BATCH 16
#define NTOK  3136
#define NHEAD 8
#define HDIM  64
#define HSP   56
#define MROWS (BATCH * NTOK)   // 50176

// Internal activation layout is head-major: buf[((b*8+h)*3136 + n)*64 + e],
// which is the flat order of (B, NH, N, HD); the reference's final
// reshape(B, N, D) is a pure reinterpret of this order.

// ---------- dtype detection: fp32 inputs read as bf16 contain huge exponents ----------
__global__ __launch_bounds__(256) void detect_dtype(const ushort* __restrict__ x,
                                                    int* __restrict__ flag)
{
    __shared__ int s;
    if (threadIdx.x == 0) s = 0;
    __syncthreads();
    int bad = 0;
    for (int i = threadIdx.x; i < 4096; i += 256) {
        int e = (x[i] >> 7) & 0xFF;
        if (e >= 0x90) bad = 1;     // |v| >= 2^17: impossible for bf16 N(0,1) data
    }
    if (bad) s = 1;                 // benign race, same value
    __syncthreads();
    if (threadIdx.x == 0) flag[0] = s;   // 1 => inputs are fp32
}

// ---------- weight transpose: WqkvT (1536x512), WpT (512x512), bf16 out ----------
__global__ __launch_bounds__(256) void prep_weights(
    const void* __restrict__ Wq, const void* __restrict__ Wkv,
    const void* __restrict__ Wp, const int* __restrict__ flag,
    ushort* __restrict__ WqkvT, ushort* __restrict__ WpT)
{
    bool f32 = flag[0] != 0;
    int idx = blockIdx.x * 256 + threadIdx.x;   // over 2048*512
    int kk = idx & 511;
    int n  = idx >> 9;                          // 0..2047
    if (n < 1536) {
        ushort val;
        if (n < 512)
            val = f32 ? f2b(((const float*)Wq)[kk * 512 + n])
                      : ((const ushort*)Wq)[kk * 512 + n];
        else
            val = f32 ? f2b(((const float*)Wkv)[kk * 1024 + (n - 512)])
                      : ((const ushort*)Wkv)[kk * 1024 + (n - 512)];
        WqkvT[n * 512 + kk] = val;
    } else {
        int n2 = n - 1536;
        WpT[n2 * 512 + kk] = f32 ? f2b(((const float*)Wp)[kk * 512 + n2])
                                 : ((const ushort*)Wp)[kk * 512 + n2];
    }
}

// ---------- MFMA GEMM: A (MxK) row-major, Bt (NcxK) bf16 row-major (= B^T) ----------
// mode 0: Nc=1536, A = x (external, dual-dtype); epilogue -> q (relu),
//         k (+pos_enc, relu), v (copy), head-major bf16
// mode 1: Nc=512, A = internal bf16; epilogue adds bias, writes d_out (dual-dtype)
#define BM 128
#define BN 128
#define BK 32
#define LDST 40   // 40 ushorts = 80 B row stride (16B multiple), breaks bank stride

__global__ __launch_bounds__(256) void gemm_bt(
    const void* __restrict__ A, const ushort* __restrict__ Bt,
    int K, int mode, const int* __restrict__ flag,
    const void* __restrict__ pos_enc, const void* __restrict__ bias,
    void* __restrict__ out0, ushort* __restrict__ out1, ushort* __restrict__ out2)
{
    __shared__ ushort Als[BM * LDST];
    __shared__ ushort Bls[BN * LDST];
    bool f32 = flag[0] != 0;
    bool a_f32 = f32 && (mode == 0);      // mode-1 A is internal bf16
    int tid  = threadIdx.x;
    int m0   = blockIdx.x * BM;
    int n0   = blockIdx.y * BN;
    int wave = tid >> 6, lane = tid & 63;
    int wm = wave & 1, wn = wave >> 1;
    int mrow = lane & 15, g = lane >> 4;

    floatx4 acc[4][4];
    #pragma unroll
    for (int i = 0; i < 4; i++)
        #pragma unroll
        for (int j = 0; j < 4; j++) acc[i][j] = (floatx4)0.f;

    for (int k0 = 0; k0 < K; k0 += BK) {
        if (a_f32) {
            const float* Af = (const float*)A;
            #pragma unroll
            for (int c = tid; c < 512; c += 256) {
                int r = c >> 2, ko = (c & 3) * 8;
                const float* p = Af + (size_t)(m0 + r) * K + k0 + ko;
                float4 f0 = *(const float4*)p;
                float4 f1 = *(const float4*)(p + 4);
                ushort t[8] = { f2b(f0.x), f2b(f0.y), f2b(f0.z), f2b(f0.w),
                                f2b(f1.x), f2b(f1.y), f2b(f1.z), f2b(f1.w) };
                *(uint4*)&Als[r * LDST + ko] = *(const uint4*)t;
            }
        } else {
            const ushort* Ab = (const ushort*)A;
            #pragma unroll
            for (int c = tid; c < 512; c += 256) {
                int r = c >> 2, ko = (c & 3) * 8;
                *(uint4*)&Als[r * LDST + ko] =
                    *(const uint4*)(Ab + (size_t)(m0 + r) * K + k0 + ko);
            }
        }
        #pragma unroll
        for (int c = tid; c < 512; c += 256) {
            int r = c >> 2, ko = (c & 3) * 8;
            *(uint4*)&Bls[r * LDST + ko] =
                *(const uint4*)(Bt + (size_t)(n0 + r) * K + k0 + ko);
        }
        __syncthreads();
        bf16x8 af[4], bfr[4];
        #pragma unroll
        for (int i = 0; i < 4; i++)
            af[i] = *(const bf16x8*)&Als[(wm * 64 + i * 16 + mrow) * LDST + g * 8];
        #pragma unroll
        for (int i = 0; i < 4; i++)
            bfr[i] = *(const bf16x8*)&Bls[(wn * 64 + i * 16 + mrow) * LDST + g * 8];
        #pragma unroll
        for (int mi = 0; mi < 4; mi++)
            #pragma unroll
            for (int ni = 0; ni < 4; ni++)
                acc[mi][ni] = __builtin_amdgcn_mfma_f32_16x16x32_bf16(
                    af[mi], bfr[ni], acc[mi][ni], 0, 0, 0);
        __syncthreads();
    }

    // D mapping (m89/m91-verified): col = lane&15, row = (lane>>4)*4 + reg
    #pragma unroll
    for (int mi = 0; mi < 4; mi++) {
        int rbase = m0 + wm * 64 + mi * 16 + g * 4;
        #pragma unroll
        for (int ni = 0; ni < 4; ni++) {
            int col = n0 + wn * 64 + ni * 16 + mrow;
            #pragma unroll
            for (int r = 0; r < 4; r++) {
                float val = acc[mi][ni][r];
                int row = rbase + r;
                if (mode == 1) {
                    float bv = f32 ? ((const float*)bias)[col]
                                   : b2f(((const ushort*)bias)[col]);
                    size_t o = (size_t)row * 512 + col;
                    if (f32) ((float*)out0)[o] = val + bv;
                    else     ((ushort*)out0)[o] = f2b(val + bv);
                } else {
                    int b = row / NTOK;
                    int n = row - b * NTOK;
                    if (col < 512) {
                        int h = col >> 6, e = col & 63;
                        size_t o = (((size_t)b * 8 + h) * NTOK + n) * 64 + e;
                        ((ushort*)out0)[o] = f2b(fmaxf(val, 0.f));
                    } else if (col < 1024) {
                        int d = col - 512;
                        int h = d >> 6, e = d & 63;
                        float pe = f32 ? ((const float*)pos_enc)[(size_t)n * 512 + d]
                                       : b2f(((const ushort*)pos_enc)[(size_t)n * 512 + d]);
                        size_t o = (((size_t)b * 8 + h) * NTOK + n) * 64 + e;
                        out1[o] = f2b(fmaxf(val + pe, 0.f));
                    } else {
                        int d = col - 1024;
                        int h = d >> 6, e = d & 63;
                        size_t o = (((size_t)b * 8 + h) * NTOK + n) * 64 + e;
                        out2[o] = f2b(val);
                    }
                }
            }
        }
    }
}

// ---------- ctx[d][e] = sum_n k[n][d] v[n][e] (64x64 per b,h) + k_sum, atomic ----------
#define SPLITS 7
#define NPER   (NTOK / SPLITS)   // 448

__global__ __launch_bounds__(256) void ctx_ksum(
    const ushort* __restrict__ kbuf, const ushort* __restrict__ vbuf,
    float* __restrict__ ctx, float* __restrict__ ksum)
{
    int bh = blockIdx.x, sp = blockIdx.y;
    int nstart = sp * NPER;
    __shared__ float kls[64 * 64];
    __shared__ float vls[64 * 64];
    int tid  = threadIdx.x;
    int lane = tid & 63;    // d
    int wave = tid >> 6;    // e-group
    float acc[16];
    #pragma unroll
    for (int i = 0; i < 16; i++) acc[i] = 0.f;
    float ks = 0.f;
    size_t base = ((size_t)bh * NTOK + nstart) * 64;   // head-major, contiguous

    for (int nc = 0; nc < NPER; nc += 64) {
        for (int c = tid; c < 512; c += 256) {
            uint4 ku = *(const uint4*)(kbuf + base + (size_t)nc * 64 + c * 8);
            uint4 vu = *(const uint4*)(vbuf + base + (size_t)nc * 64 + c * 8);
            const ushort* kp = (const ushort*)&ku;
            const ushort* vp = (const ushort*)&vu;
            #pragma unroll
            for (int j = 0; j < 8; j++) {
                kls[c * 8 + j] = b2f(kp[j]);
                vls[c * 8 + j] = b2f(vp[j]);
            }
        }
        __syncthreads();
        for (int nl = 0; nl < 64; ++nl) {
            float kd = kls[nl * 64 + lane];
            if (wave == 0) ks += kd;
            const float* vp = &vls[nl * 64 + wave * 16];
            #pragma unroll
            for (int i = 0; i < 16; i++) acc[i] += kd * vp[i];
        }
        __syncthreads();
    }
    float* cp = ctx + (size_t)bh * 4096 + lane * 64 + wave * 16;
    #pragma unroll
    for (int i = 0; i < 16; i++) atomicAdd(&cp[i], acc[i]);
    if (wave == 0) atomicAdd(&ksum[(size_t)bh * 64 + lane], ks);
}

// ---------- attn = (q @ ctx) * d_inv  -> ybuf (head-major bf16) ----------
__global__ __launch_bounds__(256) void attn_kernel(
    const ushort* __restrict__ q, const float* __restrict__ ctx,
    const float* __restrict__ ksum, ushort* __restrict__ ybuf)
{
    int bx = blockIdx.x;
    int bh = bx / 49, chunk = bx % 49;
    int n0 = chunk * 64;
    __shared__ float ctxs[4096];
    __shared__ float ksums[64];
    __shared__ float dinv[64];
    int tid = threadIdx.x;
    for (int i = tid; i < 4096; i += 256) ctxs[i] = ctx[(size_t)bh * 4096 + i];
    if (tid < 64) ksums[tid] = ksum[(size_t)bh * 64 + tid];
    __syncthreads();
    int nl = tid & 63, wave = tid >> 6;
    size_t qbase = ((size_t)bh * NTOK + n0 + nl) * 64;
    float qr[64];
    #pragma unroll
    for (int i = 0; i < 8; i++) {
        uint4 u = *(const uint4*)(q + qbase + i * 8);
        const ushort* p = (const ushort*)&u;
        #pragma unroll
        for (int j = 0; j < 8; j++) qr[i * 8 + j] = b2f(p[j]);
    }
    if (wave == 0) {
        float s = 0.f;
        #pragma unroll
        for (int d = 0; d < 64; ++d) s += qr[d] * ksums[d];
        dinv[nl] = 1.0f / (s + 1e-6f);
    }
    __syncthreads();
    float acc[16];
    #pragma unroll
    for (int i = 0; i < 16; i++) acc[i] = 0.f;
    for (int d = 0; d < 64; ++d) {
        float qd = qr[d];
        const float* c = &ctxs[d * 64 + wave * 16];
        #pragma unroll
        for (int i = 0; i < 16; i++) acc[i] += qd * c[i];
    }
    float di = dinv[nl];
    size_t obase = qbase + wave * 16;
    #pragma unroll
    for (int i = 0; i < 16; i++) ybuf[obase + i] = f2b(acc[i] * di);
}

// ---------- y += depthwise 5x5 conv(v) + bias (in place on ybuf) ----------
__global__ __launch_bounds__(256) void dwc_add(
    const ushort* __restrict__ v, const void* __restrict__ dwc_w,
    const void* __restrict__ dwc_b, const int* __restrict__ flag,
    ushort* __restrict__ ybuf)
{
    bool f32 = flag[0] != 0;
    size_t idx = (size_t)blockIdx.x * 256 + threadIdx.x;  // 25,690,112 total
    int e = (int)(idx & 63);
    size_t r = idx >> 6;            // bh*3136 + n
    int n  = (int)(r % NTOK);
    int bh = (int)(r / NTOK);
    int y = n / HSP, x = n % HSP;
    float acc = f32 ? ((const float*)dwc_b)[e] : b2f(((const ushort*)dwc_b)[e]);
    #pragma unroll
    for (int dy = 0; dy < 5; ++dy) {
        int yy = y + dy - 2;
        if (yy < 0 || yy >= HSP) continue;
        #pragma unroll
        for (int dx = 0; dx < 5; ++dx) {
            int xx = x + dx - 2;
            if (xx < 0 || xx >= HSP) continue;
            float w = f32 ? ((const float*)dwc_w)[e * 25 + dy * 5 + dx]
                          : b2f(((const ushort*)dwc_w)[e * 25 + dy * 5 + dx]);
            float vv = b2f(v[((size_t)bh * NTOK + yy * HSP + xx) * 64 + e]);
            acc += w * vv;
        }
    }
    size_t o = ((size_t)bh * NTOK + n) * 64 + e;
    ybuf[o] = f2b(acc + b2f(ybuf[o]));
}

// ---------- launch ----------
extern "C" void kernel_launch(void* const* d_in, const int* in_sizes, int n_in,
                              void* d_out, int out_size, void* d_ws, size_t ws_size,
                              hipStream_t stream) {
    const void* x    = d_in[0];
    const void* Wq   = d_in[1];
    const void* Wkv  = d_in[2];
    const void* pos  = d_in[3];
    const void* dwcw = d_in[4];
    const void* dwcb = d_in[5];
    const void* Wp   = d_in[6];
    const void* bp   = d_in[7];

    char* ws = (char*)d_ws;
    int*    flag   = (int*)(ws + 0);
    ushort* WqkvT  = (ushort*)(ws + 4096);
    ushort* WpT    = (ushort*)(ws + 4096 + 1572864);              // 1,576,960
    float*  ctx    = (float*)(ws + 2101248);                      // 128*4096*4 = 2,097,152
    float*  ksum   = (float*)(ws + 4198400);                      // 128*64*4 = 32,768
    ushort* qbuf   = (ushort*)(ws + 4231168);
    ushort* kbuf   = (ushort*)(ws + 4231168 + 51380224);          // reused as y
    ushort* vbuf   = (ushort*)(ws + 4231168 + 2ull * 51380224);
    // total ws use: 4,231,168 + 3*51,380,224 = 158,371,840 bytes

    detect_dtype<<<1, 256, 0, stream>>>((const ushort*)x, flag);

    hipMemsetAsync(ctx, 0, 2097152 + 32768, stream);   // zero ctx + ksum

    prep_weights<<<4096, 256, 0, stream>>>(Wq, Wkv, Wp, flag, WqkvT, WpT);

    gemm_bt<<<dim3(MROWS / BM, 1536 / BN), 256, 0, stream>>>(
        x, WqkvT, 512, 0, flag, pos, nullptr, qbuf, kbuf, vbuf);

    ctx_ksum<<<dim3(128, SPLITS), 256, 0, stream>>>(kbuf, vbuf, ctx, ksum);

    attn_kernel<<<128 * 49, 256, 0, stream>>>(qbuf, ctx, ksum, kbuf /* y overwrites k */);

    dwc_add<<<(int)(((size_t)MROWS * 512) / 256), 256, 0, stream>>>(
        vbuf, dwcw, dwcb, flag, kbuf);

    gemm_bt<<<dim3(MROWS / BM, 512 / BN), 256, 0, stream>>>(
        kbuf, WpT, 512, 1, flag, nullptr, bp, d_out, nullptr, nullptr);
}

// Round 4
// 1044.910 us; speedup vs baseline: 1.5780x; 1.5780x over previous
//
#include <hip/hip_runtime.h>

// ---------- bf16 helpers (raw ushort representation) ----------
__device__ __forceinline__ float b2f(ushort u) {
    union { float f; unsigned int i; } w; w.i = ((unsigned int)u) << 16; return w.f;
}
__device__ __forceinline__ ushort f2b(float f) {
    union { float f; unsigned int i; } w; w.f = f;
    unsigned int lsb = (w.i >> 16) & 1u;
    w.i += 0x7fffu + lsb;
    return (ushort)(w.i >> 16);
}

typedef __bf16 bf16x8 __attribute__((ext_vector_type(8)));
typedef float floatx4 __attribute__((ext_vector_type(4)));

// Problem constants
#define BATCH 16
#define NTOK  3136
#define NHEAD 8
#define HDIM  64
#define HSP   56
#define MROWS (BATCH * NTOK)   // 50176

// Internal activation layout is head-major: buf[((b*8+h)*3136 + n)*64 + e]
// == flat (B, NH, N, HD); the reference's final reshape(B,N,D) is a pure
// reinterpret of this order.

// ---------- dtype detection: fp32 inputs read as bf16 contain huge exponents ----------
__global__ __launch_bounds__(256) void detect_dtype(const ushort* __restrict__ x,
                                                    int* __restrict__ flag)
{
    __shared__ int s;
    if (threadIdx.x == 0) s = 0;
    __syncthreads();
    int bad = 0;
    for (int i = threadIdx.x; i < 4096; i += 256) {
        int e = (x[i] >> 7) & 0xFF;
        if (e >= 0x90) bad = 1;     // |v| >= 2^17: impossible for bf16 N(0,1) data
    }
    if (bad) s = 1;
    __syncthreads();
    if (threadIdx.x == 0) flag[0] = s;   // 1 => inputs are fp32
}

// ---------- convert x -> bf16 (or copy-through if already bf16) ----------
__global__ __launch_bounds__(256) void convert_x(
    const void* __restrict__ x, const int* __restrict__ flag,
    ushort* __restrict__ xbf)
{
    size_t t = (size_t)blockIdx.x * 256 + threadIdx.x;   // 3,211,264 threads x 8 elems
    if (flag[0]) {
        const float* xf = (const float*)x + t * 8;
        float4 f0 = *(const float4*)xf;
        float4 f1 = *(const float4*)(xf + 4);
        ushort o[8] = { f2b(f0.x), f2b(f0.y), f2b(f0.z), f2b(f0.w),
                        f2b(f1.x), f2b(f1.y), f2b(f1.z), f2b(f1.w) };
        *(uint4*)(xbf + t * 8) = *(const uint4*)o;
    } else {
        *(uint4*)(xbf + t * 8) = *((const uint4*)x + t);
    }
}

// ---------- weight transpose: WqkvT (1536x512), WpT (512x512), bf16 out ----------
__global__ __launch_bounds__(256) void prep_weights(
    const void* __restrict__ Wq, const void* __restrict__ Wkv,
    const void* __restrict__ Wp, const int* __restrict__ flag,
    ushort* __restrict__ WqkvT, ushort* __restrict__ WpT)
{
    bool f32 = flag[0] != 0;
    int idx = blockIdx.x * 256 + threadIdx.x;   // over 2048*512
    int kk = idx & 511;
    int n  = idx >> 9;                          // 0..2047
    if (n < 1536) {
        ushort val;
        if (n < 512)
            val = f32 ? f2b(((const float*)Wq)[kk * 512 + n])
                      : ((const ushort*)Wq)[kk * 512 + n];
        else
            val = f32 ? f2b(((const float*)Wkv)[kk * 1024 + (n - 512)])
                      : ((const ushort*)Wkv)[kk * 1024 + (n - 512)];
        WqkvT[n * 512 + kk] = val;
    } else {
        int n2 = n - 1536;
        WpT[n2 * 512 + kk] = f32 ? f2b(((const float*)Wp)[kk * 512 + n2])
                                 : ((const ushort*)Wp)[kk * 512 + n2];
    }
}

// ---------- prep dwc weights: wT[tap*64+e] = w[e*25+tap], + bias at [1600..1663] ----------
__global__ __launch_bounds__(256) void prep_dwc(
    const void* __restrict__ dwc_w, const void* __restrict__ dwc_b,
    const int* __restrict__ flag, float* __restrict__ wT)
{
    bool f32 = flag[0] != 0;
    for (int i = threadIdx.x; i < 1600; i += 256) {
        int e = i / 25, tap = i % 25;
        float w = f32 ? ((const float*)dwc_w)[i] : b2f(((const ushort*)dwc_w)[i]);
        wT[tap * 64 + e] = w;
    }
    if (threadIdx.x < 64) {
        float b = f32 ? ((const float*)dwc_b)[threadIdx.x]
                      : b2f(((const ushort*)dwc_b)[threadIdx.x]);
        wT[1600 + threadIdx.x] = b;
    }
}

// ---------- MFMA GEMM: A (MxK) row-major, Bt (NcxK) bf16 row-major (= B^T) ----------
// mode 0: Nc=1536; epilogue -> q (relu), k (+pos_enc, relu), v (copy), head-major bf16
// mode 1: Nc=512; epilogue adds bias, writes d_out (dual-dtype)
// a_ext: 1 => A may be external fp32 (branch on flag); 0 => A is bf16
#define BM 128
#define BN 128
#define BK 32
#define LDST 40   // 40 ushorts = 80 B row stride

__global__ __launch_bounds__(256) void gemm_bt(
    const void* __restrict__ A, const ushort* __restrict__ Bt,
    int K, int mode, int a_ext, const int* __restrict__ flag,
    const void* __restrict__ pos_enc, const void* __restrict__ bias,
    void* __restrict__ out0, ushort* __restrict__ out1, ushort* __restrict__ out2)
{
    __shared__ ushort Als[BM * LDST];
    __shared__ ushort Bls[BN * LDST];
    bool f32 = flag[0] != 0;
    bool a_f32 = f32 && a_ext;
    int tid  = threadIdx.x;
    int m0   = blockIdx.x * BM;
    int n0   = blockIdx.y * BN;
    int wave = tid >> 6, lane = tid & 63;
    int wm = wave & 1, wn = wave >> 1;
    int mrow = lane & 15, g = lane >> 4;

    floatx4 acc[4][4];
    #pragma unroll
    for (int i = 0; i < 4; i++)
        #pragma unroll
        for (int j = 0; j < 4; j++) acc[i][j] = (floatx4)0.f;

    for (int k0 = 0; k0 < K; k0 += BK) {
        if (a_f32) {
            const float* Af = (const float*)A;
            #pragma unroll
            for (int c = tid; c < 512; c += 256) {
                int r = c >> 2, ko = (c & 3) * 8;
                const float* p = Af + (size_t)(m0 + r) * K + k0 + ko;
                float4 f0 = *(const float4*)p;
                float4 f1 = *(const float4*)(p + 4);
                ushort t[8] = { f2b(f0.x), f2b(f0.y), f2b(f0.z), f2b(f0.w),
                                f2b(f1.x), f2b(f1.y), f2b(f1.z), f2b(f1.w) };
                *(uint4*)&Als[r * LDST + ko] = *(const uint4*)t;
            }
        } else {
            const ushort* Ab = (const ushort*)A;
            #pragma unroll
            for (int c = tid; c < 512; c += 256) {
                int r = c >> 2, ko = (c & 3) * 8;
                *(uint4*)&Als[r * LDST + ko] =
                    *(const uint4*)(Ab + (size_t)(m0 + r) * K + k0 + ko);
            }
        }
        #pragma unroll
        for (int c = tid; c < 512; c += 256) {
            int r = c >> 2, ko = (c & 3) * 8;
            *(uint4*)&Bls[r * LDST + ko] =
                *(const uint4*)(Bt + (size_t)(n0 + r) * K + k0 + ko);
        }
        __syncthreads();
        bf16x8 af[4], bfr[4];
        #pragma unroll
        for (int i = 0; i < 4; i++)
            af[i] = *(const bf16x8*)&Als[(wm * 64 + i * 16 + mrow) * LDST + g * 8];
        #pragma unroll
        for (int i = 0; i < 4; i++)
            bfr[i] = *(const bf16x8*)&Bls[(wn * 64 + i * 16 + mrow) * LDST + g * 8];
        #pragma unroll
        for (int mi = 0; mi < 4; mi++)
            #pragma unroll
            for (int ni = 0; ni < 4; ni++)
                acc[mi][ni] = __builtin_amdgcn_mfma_f32_16x16x32_bf16(
                    af[mi], bfr[ni], acc[mi][ni], 0, 0, 0);
        __syncthreads();
    }

    // D mapping (m89/m91-verified): col = lane&15, row = (lane>>4)*4 + reg
    #pragma unroll
    for (int mi = 0; mi < 4; mi++) {
        int rbase = m0 + wm * 64 + mi * 16 + g * 4;
        #pragma unroll
        for (int ni = 0; ni < 4; ni++) {
            int col = n0 + wn * 64 + ni * 16 + mrow;
            #pragma unroll
            for (int r = 0; r < 4; r++) {
                float val = acc[mi][ni][r];
                int row = rbase + r;
                if (mode == 1) {
                    float bv = f32 ? ((const float*)bias)[col]
                                   : b2f(((const ushort*)bias)[col]);
                    size_t o = (size_t)row * 512 + col;
                    if (f32) ((float*)out0)[o] = val + bv;
                    else     ((ushort*)out0)[o] = f2b(val + bv);
                } else {
                    int b = row / NTOK;
                    int n = row - b * NTOK;
                    if (col < 512) {
                        int h = col >> 6, e = col & 63;
                        size_t o = (((size_t)b * 8 + h) * NTOK + n) * 64 + e;
                        ((ushort*)out0)[o] = f2b(fmaxf(val, 0.f));
                    } else if (col < 1024) {
                        int d = col - 512;
                        int h = d >> 6, e = d & 63;
                        float pe = f32 ? ((const float*)pos_enc)[(size_t)n * 512 + d]
                                       : b2f(((const ushort*)pos_enc)[(size_t)n * 512 + d]);
                        size_t o = (((size_t)b * 8 + h) * NTOK + n) * 64 + e;
                        out1[o] = f2b(fmaxf(val + pe, 0.f));
                    } else {
                        int d = col - 1024;
                        int h = d >> 6, e = d & 63;
                        size_t o = (((size_t)b * 8 + h) * NTOK + n) * 64 + e;
                        out2[o] = f2b(val);
                    }
                }
            }
        }
    }
}

// ---------- ctx[d][e] = sum_n k[n][d] v[n][e] (64x64 per b,h) + k_sum, atomic ----------
#define SPLITS 7
#define NPER   (NTOK / SPLITS)   // 448

__global__ __launch_bounds__(256) void ctx_ksum(
    const ushort* __restrict__ kbuf, const ushort* __restrict__ vbuf,
    float* __restrict__ ctx, float* __restrict__ ksum)
{
    int bh = blockIdx.x, sp = blockIdx.y;
    int nstart = sp * NPER;
    __shared__ float kls[64 * 64];
    __shared__ float vls[64 * 64];
    int tid  = threadIdx.x;
    int lane = tid & 63;    // d
    int wave = tid >> 6;    // e-group
    float acc[16];
    #pragma unroll
    for (int i = 0; i < 16; i++) acc[i] = 0.f;
    float ks = 0.f;
    size_t base = ((size_t)bh * NTOK + nstart) * 64;

    for (int nc = 0; nc < NPER; nc += 64) {
        for (int c = tid; c < 512; c += 256) {
            uint4 ku = *(const uint4*)(kbuf + base + (size_t)nc * 64 + c * 8);
            uint4 vu = *(const uint4*)(vbuf + base + (size_t)nc * 64 + c * 8);
            const ushort* kp = (const ushort*)&ku;
            const ushort* vp = (const ushort*)&vu;
            #pragma unroll
            for (int j = 0; j < 8; j++) {
                kls[c * 8 + j] = b2f(kp[j]);
                vls[c * 8 + j] = b2f(vp[j]);
            }
        }
        __syncthreads();
        for (int nl = 0; nl < 64; ++nl) {
            float kd = kls[nl * 64 + lane];
            if (wave == 0) ks += kd;
            const float* vp = &vls[nl * 64 + wave * 16];
            #pragma unroll
            for (int i = 0; i < 16; i++) acc[i] += kd * vp[i];
        }
        __syncthreads();
    }
    float* cp = ctx + (size_t)bh * 4096 + lane * 64 + wave * 16;
    #pragma unroll
    for (int i = 0; i < 16; i++) atomicAdd(&cp[i], acc[i]);
    if (wave == 0) atomicAdd(&ksum[(size_t)bh * 64 + lane], ks);
}

// ---------- attn = (q @ ctx) * d_inv  -> ybuf (head-major bf16) ----------
__global__ __launch_bounds__(256) void attn_kernel(
    const ushort* __restrict__ q, const float* __restrict__ ctx,
    const float* __restrict__ ksum, ushort* __restrict__ ybuf)
{
    int bx = blockIdx.x;
    int bh = bx / 49, chunk = bx % 49;
    int n0 = chunk * 64;
    __shared__ float ctxs[4096];
    __shared__ float ksums[64];
    __shared__ float dinv[64];
    int tid = threadIdx.x;
    for (int i = tid; i < 4096; i += 256) ctxs[i] = ctx[(size_t)bh * 4096 + i];
    if (tid < 64) ksums[tid] = ksum[(size_t)bh * 64 + tid];
    __syncthreads();
    int nl = tid & 63, wave = tid >> 6;
    size_t qbase = ((size_t)bh * NTOK + n0 + nl) * 64;
    float qr[64];
    #pragma unroll
    for (int i = 0; i < 8; i++) {
        uint4 u = *(const uint4*)(q + qbase + i * 8);
        const ushort* p = (const ushort*)&u;
        #pragma unroll
        for (int j = 0; j < 8; j++) qr[i * 8 + j] = b2f(p[j]);
    }
    if (wave == 0) {
        float s = 0.f;
        #pragma unroll
        for (int d = 0; d < 64; ++d) s += qr[d] * ksums[d];
        dinv[nl] = 1.0f / (s + 1e-6f);
    }
    __syncthreads();
    float acc[16];
    #pragma unroll
    for (int i = 0; i < 16; i++) acc[i] = 0.f;
    for (int d = 0; d < 64; ++d) {
        float qd = qr[d];
        const float* c = &ctxs[d * 64 + wave * 16];
        #pragma unroll
        for (int i = 0; i < 16; i++) acc[i] += qd * c[i];
    }
    float di = dinv[nl];
    size_t obase = qbase + wave * 16;
    #pragma unroll
    for (int i = 0; i < 16; i++) ybuf[obase + i] = f2b(acc[i] * di);
}

// ---------- y += depthwise 5x5 conv(v) + bias, 8-wide vectorized ----------
__global__ __launch_bounds__(256) void dwc_add(
    const ushort* __restrict__ v, const float* __restrict__ wT,
    ushort* __restrict__ ybuf)
{
    __shared__ float wls[1664];        // 25 taps x 64 e + 64 bias
    for (int i = threadIdx.x; i < 1664; i += 256) wls[i] = wT[i];
    __syncthreads();

    int t = blockIdx.x * 256 + threadIdx.x;   // 3,211,264 total
    int eg = (t & 7) * 8;                      // e base (0,8,...,56)
    int r = t >> 3;                            // bh*3136 + n
    int n  = r % NTOK;
    int bh = r / NTOK;
    int y = n / HSP, x = n % HSP;

    float acc[8];
    #pragma unroll
    for (int j = 0; j < 8; j++) acc[j] = wls[1600 + eg + j];

    const ushort* vb = v + (size_t)bh * NTOK * 64 + eg;
    #pragma unroll
    for (int dy = 0; dy < 5; ++dy) {
        int yy = y + dy - 2;
        if (yy < 0 || yy >= HSP) continue;
        #pragma unroll
        for (int dx = 0; dx < 5; ++dx) {
            int xx = x + dx - 2;
            if (xx < 0 || xx >= HSP) continue;
            uint4 u = *(const uint4*)(vb + (size_t)(yy * HSP + xx) * 64);
            const ushort* up = (const ushort*)&u;
            const float* wp = &wls[(dy * 5 + dx) * 64 + eg];
            #pragma unroll
            for (int j = 0; j < 8; j++) acc[j] += wp[j] * b2f(up[j]);
        }
    }
    size_t o = (size_t)r * 64 + eg;
    uint4 yo = *(const uint4*)(ybuf + o);
    const ushort* yp = (const ushort*)&yo;
    ushort res[8];
    #pragma unroll
    for (int j = 0; j < 8; j++) res[j] = f2b(acc[j] + b2f(yp[j]));
    *(uint4*)(ybuf + o) = *(const uint4*)res;
}

// ---------- launch ----------
extern "C" void kernel_launch(void* const* d_in, const int* in_sizes, int n_in,
                              void* d_out, int out_size, void* d_ws, size_t ws_size,
                              hipStream_t stream) {
    const void* x    = d_in[0];
    const void* Wq   = d_in[1];
    const void* Wkv  = d_in[2];
    const void* pos  = d_in[3];
    const void* dwcw = d_in[4];
    const void* dwcb = d_in[5];
    const void* Wp   = d_in[6];
    const void* bp   = d_in[7];

    char* ws = (char*)d_ws;
    const size_t SZ_BIG = 51380224;                    // 50176*512*2
    int*    flag   = (int*)(ws + 0);
    ushort* WqkvT  = (ushort*)(ws + 4096);
    ushort* WpT    = (ushort*)(ws + 4096 + 1572864);
    float*  wTdwc  = (float*)(ws + 2101248);           // 1664 floats = 6656 B
    float*  ctx    = (float*)(ws + 2107904);           // 2,097,152
    float*  ksum   = (float*)(ws + 4205056);           // 32,768
    ushort* qbuf   = (ushort*)(ws + 4237824);
    ushort* kbuf   = (ushort*)(ws + 4237824 + SZ_BIG);     // reused as y
    ushort* vbuf   = (ushort*)(ws + 4237824 + 2 * SZ_BIG);
    ushort* xbf    = (ushort*)(ws + 4237824 + 3 * SZ_BIG);
    const size_t WS_NEED_XBF = 4237824 + 4 * SZ_BIG;   // 209,758,720
    bool use_xbf = ws_size >= WS_NEED_XBF;

    detect_dtype<<<1, 256, 0, stream>>>((const ushort*)x, flag);
    hipMemsetAsync(ctx, 0, 2097152 + 32768, stream);

    prep_weights<<<4096, 256, 0, stream>>>(Wq, Wkv, Wp, flag, WqkvT, WpT);
    prep_dwc<<<1, 256, 0, stream>>>(dwcw, dwcb, flag, wTdwc);

    const void* Ag = x;
    int a_ext = 1;
    if (use_xbf) {
        convert_x<<<12544, 256, 0, stream>>>(x, flag, xbf);
        Ag = xbf; a_ext = 0;
    }

    gemm_bt<<<dim3(MROWS / BM, 1536 / BN), 256, 0, stream>>>(
        Ag, WqkvT, 512, 0, a_ext, flag, pos, nullptr, qbuf, kbuf, vbuf);

    ctx_ksum<<<dim3(128, SPLITS), 256, 0, stream>>>(kbuf, vbuf, ctx, ksum);

    attn_kernel<<<128 * 49, 256, 0, stream>>>(qbuf, ctx, ksum, kbuf /* y overwrites k */);

    dwc_add<<<12544, 256, 0, stream>>>(vbuf, wTdwc, kbuf);

    gemm_bt<<<dim3(MROWS / BM, 512 / BN), 256, 0, stream>>>(
        kbuf, WpT, 512, 1, 0, flag, nullptr, bp, d_out, nullptr, nullptr);
}

// Round 5
// 948.011 us; speedup vs baseline: 1.7393x; 1.1022x over previous
//
#include <hip/hip_runtime.h>

// ---------- bf16 helpers (raw ushort representation) ----------
__device__ __forceinline__ float b2f(ushort u) {
    union { float f; unsigned int i; } w; w.i = ((unsigned int)u) << 16; return w.f;
}
__device__ __forceinline__ ushort f2b(float f) {
    union { float f; unsigned int i; } w; w.f = f;
    unsigned int lsb = (w.i >> 16) & 1u;
    w.i += 0x7fffu + lsb;
    return (ushort)(w.i >> 16);
}

typedef __bf16 bf16x8 __attribute__((ext_vector_type(8)));
typedef float floatx4 __attribute__((ext_vector_type(4)));

// async global->LDS, 16B per lane; lane i lands at lds_base + i*16B (HW rule)
__device__ __forceinline__ void async_copy16(ushort* lds_base, const ushort* gptr) {
    __builtin_amdgcn_global_load_lds(
        (const __attribute__((address_space(1))) unsigned int*)gptr,
        (__attribute__((address_space(3))) unsigned int*)lds_base,
        16, 0, 0);
}

// Problem constants
#define BATCH 16
#define NTOK  3136
#define NHEAD 8
#define HDIM  64
#define HSP   56
#define MROWS (BATCH * NTOK)   // 50176

// Internal activation layout is head-major: buf[((b*8+h)*3136 + n)*64 + e]
// == flat (B, NH, N, HD); the reference's final reshape(B,N,D) is a pure
// reinterpret of this order.

// ---------- dtype detection: fp32 inputs read as bf16 contain huge exponents ----------
__global__ __launch_bounds__(256) void detect_dtype(const ushort* __restrict__ x,
                                                    int* __restrict__ flag)
{
    __shared__ int s;
    if (threadIdx.x == 0) s = 0;
    __syncthreads();
    int bad = 0;
    for (int i = threadIdx.x; i < 4096; i += 256) {
        int e = (x[i] >> 7) & 0xFF;
        if (e >= 0x90) bad = 1;     // |v| >= 2^17: impossible for bf16 N(0,1) data
    }
    if (bad) s = 1;
    __syncthreads();
    if (threadIdx.x == 0) flag[0] = s;   // 1 => inputs are fp32
}

// ---------- convert x -> bf16 (or copy-through if already bf16) ----------
__global__ __launch_bounds__(256) void convert_x(
    const void* __restrict__ x, const int* __restrict__ flag,
    ushort* __restrict__ xbf)
{
    size_t t = (size_t)blockIdx.x * 256 + threadIdx.x;   // 3,211,264 threads x 8 elems
    if (flag[0]) {
        const float* xf = (const float*)x + t * 8;
        float4 f0 = *(const float4*)xf;
        float4 f1 = *(const float4*)(xf + 4);
        ushort o[8] = { f2b(f0.x), f2b(f0.y), f2b(f0.z), f2b(f0.w),
                        f2b(f1.x), f2b(f1.y), f2b(f1.z), f2b(f1.w) };
        *(uint4*)(xbf + t * 8) = *(const uint4*)o;
    } else {
        *(uint4*)(xbf + t * 8) = *((const uint4*)x + t);
    }
}

// ---------- weight transpose: WqkvT (1536x512), WpT (512x512), bf16 out ----------
__global__ __launch_bounds__(256) void prep_weights(
    const void* __restrict__ Wq, const void* __restrict__ Wkv,
    const void* __restrict__ Wp, const int* __restrict__ flag,
    ushort* __restrict__ WqkvT, ushort* __restrict__ WpT)
{
    bool f32 = flag[0] != 0;
    int idx = blockIdx.x * 256 + threadIdx.x;   // over 2048*512
    int kk = idx & 511;
    int n  = idx >> 9;                          // 0..2047
    if (n < 1536) {
        ushort val;
        if (n < 512)
            val = f32 ? f2b(((const float*)Wq)[kk * 512 + n])
                      : ((const ushort*)Wq)[kk * 512 + n];
        else
            val = f32 ? f2b(((const float*)Wkv)[kk * 1024 + (n - 512)])
                      : ((const ushort*)Wkv)[kk * 1024 + (n - 512)];
        WqkvT[n * 512 + kk] = val;
    } else {
        int n2 = n - 1536;
        WpT[n2 * 512 + kk] = f32 ? f2b(((const float*)Wp)[kk * 512 + n2])
                                 : ((const ushort*)Wp)[kk * 512 + n2];
    }
}

// ---------- prep dwc weights: wT[tap*64+e] = w[e*25+tap], + bias at [1600..1663] ----------
__global__ __launch_bounds__(256) void prep_dwc(
    const void* __restrict__ dwc_w, const void* __restrict__ dwc_b,
    const int* __restrict__ flag, float* __restrict__ wT)
{
    bool f32 = flag[0] != 0;
    for (int i = threadIdx.x; i < 1600; i += 256) {
        int e = i / 25, tap = i % 25;
        float w = f32 ? ((const float*)dwc_w)[i] : b2f(((const ushort*)dwc_w)[i]);
        wT[tap * 64 + e] = w;
    }
    if (threadIdx.x < 64) {
        float b = f32 ? ((const float*)dwc_b)[threadIdx.x]
                      : b2f(((const ushort*)dwc_b)[threadIdx.x]);
        wT[1600 + threadIdx.x] = b;
    }
}

// ---------- MFMA GEMM (async LDS staging): A (MxK) bf16, Bt (NcxK) bf16 ----------
// grid = (Nc/BN, M/BM): blockIdx.x = n-block (fast) so same-A blocks are
// temporally adjacent -> A tile re-reads hit L2/L3.
// mode 0: epilogue -> q (relu), k (+pos_enc, relu), v (copy), head-major bf16
// mode 1: epilogue adds bias, writes d_out (fp32 or bf16 per flag)
#define BM 128
#define BN 128
#define BK 32
// LDS tile: row-major [row][k], 32 ushorts (64 B) per row, NO padding
// (global_load_lds requires base + lane*16 contiguity). Bank conflicts broken
// by XOR segment swizzle: LDS[row][seg] holds global 16B-seg (seg ^ swz(row)).
__device__ __forceinline__ int swz(int r) { return (r ^ (r >> 2)) & 3; }

__global__ __launch_bounds__(256) void gemm_bt(
    const ushort* __restrict__ A, const ushort* __restrict__ Bt,
    int K, int mode, const int* __restrict__ flag,
    const void* __restrict__ pos_enc, const void* __restrict__ bias,
    void* __restrict__ out0, ushort* __restrict__ out1, ushort* __restrict__ out2)
{
    __shared__ ushort Als[BM * BK];   // 8 KB
    __shared__ ushort Bls[BN * BK];   // 8 KB
    bool f32 = flag[0] != 0;
    int tid  = threadIdx.x;
    int n0   = blockIdx.x * BN;
    int m0   = blockIdx.y * BM;
    int wave = tid >> 6, lane = tid & 63;
    int wm = wave & 1, wn = wave >> 1;
    int mrow = lane & 15, g = lane >> 4;

    // staging indices for this thread's two DMA instructions per tile
    // instruction t (0..7): covers linear li = t*64 + lane; row = li>>2, seg = li&3
    int t0 = wave * 2;
    int li0 = t0 * 64 + lane, li1 = (t0 + 1) * 64 + lane;
    int r0 = li0 >> 2, s0 = (li0 & 3) ^ swz(li0 >> 2);
    int r1 = li1 >> 2, s1 = (li1 & 3) ^ swz(li1 >> 2);

    floatx4 acc[4][4];
    #pragma unroll
    for (int i = 0; i < 4; i++)
        #pragma unroll
        for (int j = 0; j < 4; j++) acc[i][j] = (floatx4)0.f;

    const ushort* Arow0 = A + (size_t)(m0 + r0) * K + s0 * 8;
    const ushort* Arow1 = A + (size_t)(m0 + r1) * K + s1 * 8;
    const ushort* Brow0 = Bt + (size_t)(n0 + r0) * K + s0 * 8;
    const ushort* Brow1 = Bt + (size_t)(n0 + r1) * K + s1 * 8;

    for (int k0 = 0; k0 < K; k0 += BK) {
        async_copy16(&Als[t0 * 512],       Arow0 + k0);
        async_copy16(&Als[(t0 + 1) * 512], Arow1 + k0);
        async_copy16(&Bls[t0 * 512],       Brow0 + k0);
        async_copy16(&Bls[(t0 + 1) * 512], Brow1 + k0);
        __syncthreads();   // drains vmcnt (LDS-DMA) + lgkm

        bf16x8 af[4], bfr[4];
        #pragma unroll
        for (int i = 0; i < 4; i++) {
            int r = wm * 64 + i * 16 + mrow;
            af[i] = *(const bf16x8*)&Als[r * 32 + (g ^ swz(r)) * 8];
        }
        #pragma unroll
        for (int i = 0; i < 4; i++) {
            int r = wn * 64 + i * 16 + mrow;
            bfr[i] = *(const bf16x8*)&Bls[r * 32 + (g ^ swz(r)) * 8];
        }
        #pragma unroll
        for (int mi = 0; mi < 4; mi++)
            #pragma unroll
            for (int ni = 0; ni < 4; ni++)
                acc[mi][ni] = __builtin_amdgcn_mfma_f32_16x16x32_bf16(
                    af[mi], bfr[ni], acc[mi][ni], 0, 0, 0);
        __syncthreads();
    }

    // D mapping (m89/m91-verified): col = lane&15, row = (lane>>4)*4 + reg
    #pragma unroll
    for (int mi = 0; mi < 4; mi++) {
        int rbase = m0 + wm * 64 + mi * 16 + g * 4;
        #pragma unroll
        for (int ni = 0; ni < 4; ni++) {
            int col = n0 + wn * 64 + ni * 16 + mrow;
            #pragma unroll
            for (int r = 0; r < 4; r++) {
                float val = acc[mi][ni][r];
                int row = rbase + r;
                if (mode == 1) {
                    float bv = f32 ? ((const float*)bias)[col]
                                   : b2f(((const ushort*)bias)[col]);
                    size_t o = (size_t)row * 512 + col;
                    if (f32) ((float*)out0)[o] = val + bv;
                    else     ((ushort*)out0)[o] = f2b(val + bv);
                } else {
                    int b = row / NTOK;
                    int n = row - b * NTOK;
                    if (col < 512) {
                        int h = col >> 6, e = col & 63;
                        size_t o = (((size_t)b * 8 + h) * NTOK + n) * 64 + e;
                        ((ushort*)out0)[o] = f2b(fmaxf(val, 0.f));
                    } else if (col < 1024) {
                        int d = col - 512;
                        int h = d >> 6, e = d & 63;
                        float pe = f32 ? ((const float*)pos_enc)[(size_t)n * 512 + d]
                                       : b2f(((const ushort*)pos_enc)[(size_t)n * 512 + d]);
                        size_t o = (((size_t)b * 8 + h) * NTOK + n) * 64 + e;
                        out1[o] = f2b(fmaxf(val + pe, 0.f));
                    } else {
                        int d = col - 1024;
                        int h = d >> 6, e = d & 63;
                        size_t o = (((size_t)b * 8 + h) * NTOK + n) * 64 + e;
                        out2[o] = f2b(val);
                    }
                }
            }
        }
    }
}

// ---------- ctx[d][e] = sum_n k[n][d] v[n][e] (64x64 per b,h) + k_sum, atomic ----------
#define SPLITS 7
#define NPER   (NTOK / SPLITS)   // 448

__global__ __launch_bounds__(256) void ctx_ksum(
    const ushort* __restrict__ kbuf, const ushort* __restrict__ vbuf,
    float* __restrict__ ctx, float* __restrict__ ksum)
{
    int bh = blockIdx.x, sp = blockIdx.y;
    int nstart = sp * NPER;
    __shared__ float kls[64 * 64];
    __shared__ float vls[64 * 64];
    int tid  = threadIdx.x;
    int lane = tid & 63;    // d
    int wave = tid >> 6;    // e-group
    float acc[16];
    #pragma unroll
    for (int i = 0; i < 16; i++) acc[i] = 0.f;
    float ks = 0.f;
    size_t base = ((size_t)bh * NTOK + nstart) * 64;

    for (int nc = 0; nc < NPER; nc += 64) {
        for (int c = tid; c < 512; c += 256) {
            uint4 ku = *(const uint4*)(kbuf + base + (size_t)nc * 64 + c * 8);
            uint4 vu = *(const uint4*)(vbuf + base + (size_t)nc * 64 + c * 8);
            const ushort* kp = (const ushort*)&ku;
            const ushort* vp = (const ushort*)&vu;
            #pragma unroll
            for (int j = 0; j < 8; j++) {
                kls[c * 8 + j] = b2f(kp[j]);
                vls[c * 8 + j] = b2f(vp[j]);
            }
        }
        __syncthreads();
        for (int nl = 0; nl < 64; ++nl) {
            float kd = kls[nl * 64 + lane];
            if (wave == 0) ks += kd;
            const float* vp = &vls[nl * 64 + wave * 16];
            #pragma unroll
            for (int i = 0; i < 16; i++) acc[i] += kd * vp[i];
        }
        __syncthreads();
    }
    float* cp = ctx + (size_t)bh * 4096 + lane * 64 + wave * 16;
    #pragma unroll
    for (int i = 0; i < 16; i++) atomicAdd(&cp[i], acc[i]);
    if (wave == 0) atomicAdd(&ksum[(size_t)bh * 64 + lane], ks);
}

// ---------- attn = (q @ ctx) * d_inv  -> ybuf (head-major bf16) ----------
__global__ __launch_bounds__(256) void attn_kernel(
    const ushort* __restrict__ q, const float* __restrict__ ctx,
    const float* __restrict__ ksum, ushort* __restrict__ ybuf)
{
    int bx = blockIdx.x;
    int bh = bx / 49, chunk = bx % 49;
    int n0 = chunk * 64;
    __shared__ float ctxs[4096];
    __shared__ float ksums[64];
    __shared__ float dinv[64];
    int tid = threadIdx.x;
    for (int i = tid; i < 4096; i += 256) ctxs[i] = ctx[(size_t)bh * 4096 + i];
    if (tid < 64) ksums[tid] = ksum[(size_t)bh * 64 + tid];
    __syncthreads();
    int nl = tid & 63, wave = tid >> 6;
    size_t qbase = ((size_t)bh * NTOK + n0 + nl) * 64;
    float qr[64];
    #pragma unroll
    for (int i = 0; i < 8; i++) {
        uint4 u = *(const uint4*)(q + qbase + i * 8);
        const ushort* p = (const ushort*)&u;
        #pragma unroll
        for (int j = 0; j < 8; j++) qr[i * 8 + j] = b2f(p[j]);
    }
    if (wave == 0) {
        float s = 0.f;
        #pragma unroll
        for (int d = 0; d < 64; ++d) s += qr[d] * ksums[d];
        dinv[nl] = 1.0f / (s + 1e-6f);
    }
    __syncthreads();
    float acc[16];
    #pragma unroll
    for (int i = 0; i < 16; i++) acc[i] = 0.f;
    for (int d = 0; d < 64; ++d) {
        float qd = qr[d];
        const float* c = &ctxs[d * 64 + wave * 16];
        #pragma unroll
        for (int i = 0; i < 16; i++) acc[i] += qd * c[i];
    }
    float di = dinv[nl];
    size_t obase = qbase + wave * 16;
    #pragma unroll
    for (int i = 0; i < 16; i++) ybuf[obase + i] = f2b(acc[i] * di);
}

// ---------- y += depthwise 5x5 conv(v) + bias, 8-wide vectorized ----------
__global__ __launch_bounds__(256) void dwc_add(
    const ushort* __restrict__ v, const float* __restrict__ wT,
    ushort* __restrict__ ybuf)
{
    __shared__ float wls[1664];        // 25 taps x 64 e + 64 bias
    for (int i = threadIdx.x; i < 1664; i += 256) wls[i] = wT[i];
    __syncthreads();

    int t = blockIdx.x * 256 + threadIdx.x;   // 3,211,264 total
    int eg = (t & 7) * 8;                      // e base (0,8,...,56)
    int r = t >> 3;                            // bh*3136 + n
    int n  = r % NTOK;
    int bh = r / NTOK;
    int y = n / HSP, x = n % HSP;

    float acc[8];
    #pragma unroll
    for (int j = 0; j < 8; j++) acc[j] = wls[1600 + eg + j];

    const ushort* vb = v + (size_t)bh * NTOK * 64 + eg;
    #pragma unroll
    for (int dy = 0; dy < 5; ++dy) {
        int yy = y + dy - 2;
        if (yy < 0 || yy >= HSP) continue;
        #pragma unroll
        for (int dx = 0; dx < 5; ++dx) {
            int xx = x + dx - 2;
            if (xx < 0 || xx >= HSP) continue;
            uint4 u = *(const uint4*)(vb + (size_t)(yy * HSP + xx) * 64);
            const ushort* up = (const ushort*)&u;
            const float* wp = &wls[(dy * 5 + dx) * 64 + eg];
            #pragma unroll
            for (int j = 0; j < 8; j++) acc[j] += wp[j] * b2f(up[j]);
        }
    }
    size_t o = (size_t)r * 64 + eg;
    uint4 yo = *(const uint4*)(ybuf + o);
    const ushort* yp = (const ushort*)&yo;
    ushort res[8];
    #pragma unroll
    for (int j = 0; j < 8; j++) res[j] = f2b(acc[j] + b2f(yp[j]));
    *(uint4*)(ybuf + o) = *(const uint4*)res;
}

// ---------- launch ----------
extern "C" void kernel_launch(void* const* d_in, const int* in_sizes, int n_in,
                              void* d_out, int out_size, void* d_ws, size_t ws_size,
                              hipStream_t stream) {
    const void* x    = d_in[0];
    const void* Wq   = d_in[1];
    const void* Wkv  = d_in[2];
    const void* pos  = d_in[3];
    const void* dwcw = d_in[4];
    const void* dwcb = d_in[5];
    const void* Wp   = d_in[6];
    const void* bp   = d_in[7];

    char* ws = (char*)d_ws;
    const size_t SZ_BIG = 51380224;                    // 50176*512*2
    int*    flag   = (int*)(ws + 0);
    ushort* WqkvT  = (ushort*)(ws + 4096);
    ushort* WpT    = (ushort*)(ws + 4096 + 1572864);
    float*  wTdwc  = (float*)(ws + 2101248);           // 1664 floats
    float*  ctx    = (float*)(ws + 2107904);           // 2,097,152
    float*  ksum   = (float*)(ws + 4205056);           // 32,768
    ushort* qbuf   = (ushort*)(ws + 4237824);
    ushort* kbuf   = (ushort*)(ws + 4237824 + SZ_BIG);     // reused as y
    ushort* vbuf   = (ushort*)(ws + 4237824 + 2 * SZ_BIG);
    // total ws use: 4,237,824 + 3*51,380,224 = 158,378,496 bytes
    // xbf scratch lives in d_out (>= 51.4 MB whether out is fp32 or bf16);
    // dead before gemm2 writes d_out.
    ushort* xbf = (ushort*)d_out;

    detect_dtype<<<1, 256, 0, stream>>>((const ushort*)x, flag);
    hipMemsetAsync(ctx, 0, 2097152 + 32768, stream);

    prep_weights<<<4096, 256, 0, stream>>>(Wq, Wkv, Wp, flag, WqkvT, WpT);
    prep_dwc<<<1, 256, 0, stream>>>(dwcw, dwcb, flag, wTdwc);
    convert_x<<<12544, 256, 0, stream>>>(x, flag, xbf);

    gemm_bt<<<dim3(1536 / BN, MROWS / BM), 256, 0, stream>>>(
        xbf, WqkvT, 512, 0, flag, pos, nullptr, qbuf, kbuf, vbuf);

    ctx_ksum<<<dim3(128, SPLITS), 256, 0, stream>>>(kbuf, vbuf, ctx, ksum);

    attn_kernel<<<128 * 49, 256, 0, stream>>>(qbuf, ctx, ksum, kbuf /* y overwrites k */);

    dwc_add<<<12544, 256, 0, stream>>>(vbuf, wTdwc, kbuf);

    gemm_bt<<<dim3(512 / BN, MROWS / BM), 256, 0, stream>>>(
        kbuf, WpT, 512, 1, flag, nullptr, bp, d_out, nullptr, nullptr);
}

// Round 6
// 837.355 us; speedup vs baseline: 1.9691x; 1.1321x over previous
//
#include <hip/hip_runtime.h>

// ---------- bf16 helpers (raw ushort representation) ----------
__device__ __forceinline__ float b2f(ushort u) {
    union { float f; unsigned int i; } w; w.i = ((unsigned int)u) << 16; return w.f;
}
__device__ __forceinline__ ushort f2b(float f) {
    union { float f; unsigned int i; } w; w.f = f;
    unsigned int lsb = (w.i >> 16) & 1u;
    w.i += 0x7fffu + lsb;
    return (ushort)(w.i >> 16);
}

typedef __bf16 bf16x8 __attribute__((ext_vector_type(8)));
typedef float floatx4 __attribute__((ext_vector_type(4)));

// async global->LDS, 16B per lane; lane i lands at lds_base + i*16B (HW rule)
__device__ __forceinline__ void async_copy16(ushort* lds_base, const ushort* gptr) {
    __builtin_amdgcn_global_load_lds(
        (const __attribute__((address_space(1))) unsigned int*)gptr,
        (__attribute__((address_space(3))) unsigned int*)lds_base,
        16, 0, 0);
}

// Problem constants
#define BATCH 16
#define NTOK  3136
#define NHEAD 8
#define HDIM  64
#define HSP   56
#define MROWS (BATCH * NTOK)   // 50176
#define KDIM  512              // both GEMMs have K = 512

// ---------- dtype detection ----------
__global__ __launch_bounds__(256) void detect_dtype(const ushort* __restrict__ x,
                                                    int* __restrict__ flag)
{
    __shared__ int s;
    if (threadIdx.x == 0) s = 0;
    __syncthreads();
    int bad = 0;
    for (int i = threadIdx.x; i < 4096; i += 256) {
        int e = (x[i] >> 7) & 0xFF;
        if (e >= 0x90) bad = 1;
    }
    if (bad) s = 1;
    __syncthreads();
    if (threadIdx.x == 0) flag[0] = s;   // 1 => inputs are fp32
}

// ---------- convert x -> bf16 ----------
__global__ __launch_bounds__(256) void convert_x(
    const void* __restrict__ x, const int* __restrict__ flag,
    ushort* __restrict__ xbf)
{
    size_t t = (size_t)blockIdx.x * 256 + threadIdx.x;
    if (flag[0]) {
        const float* xf = (const float*)x + t * 8;
        float4 f0 = *(const float4*)xf;
        float4 f1 = *(const float4*)(xf + 4);
        ushort o[8] = { f2b(f0.x), f2b(f0.y), f2b(f0.z), f2b(f0.w),
                        f2b(f1.x), f2b(f1.y), f2b(f1.z), f2b(f1.w) };
        *(uint4*)(xbf + t * 8) = *(const uint4*)o;
    } else {
        *(uint4*)(xbf + t * 8) = *((const uint4*)x + t);
    }
}

// ---------- weight transpose ----------
__global__ __launch_bounds__(256) void prep_weights(
    const void* __restrict__ Wq, const void* __restrict__ Wkv,
    const void* __restrict__ Wp, const int* __restrict__ flag,
    ushort* __restrict__ WqkvT, ushort* __restrict__ WpT)
{
    bool f32 = flag[0] != 0;
    int idx = blockIdx.x * 256 + threadIdx.x;
    int kk = idx & 511;
    int n  = idx >> 9;
    if (n < 1536) {
        ushort val;
        if (n < 512)
            val = f32 ? f2b(((const float*)Wq)[kk * 512 + n])
                      : ((const ushort*)Wq)[kk * 512 + n];
        else
            val = f32 ? f2b(((const float*)Wkv)[kk * 1024 + (n - 512)])
                      : ((const ushort*)Wkv)[kk * 1024 + (n - 512)];
        WqkvT[n * 512 + kk] = val;
    } else {
        int n2 = n - 1536;
        WpT[n2 * 512 + kk] = f32 ? f2b(((const float*)Wp)[kk * 512 + n2])
                                 : ((const ushort*)Wp)[kk * 512 + n2];
    }
}

// ---------- prep dwc weights ----------
__global__ __launch_bounds__(256) void prep_dwc(
    const void* __restrict__ dwc_w, const void* __restrict__ dwc_b,
    const int* __restrict__ flag, float* __restrict__ wT)
{
    bool f32 = flag[0] != 0;
    for (int i = threadIdx.x; i < 1600; i += 256) {
        int e = i / 25, tap = i % 25;
        float w = f32 ? ((const float*)dwc_w)[i] : b2f(((const ushort*)dwc_w)[i]);
        wT[tap * 64 + e] = w;
    }
    if (threadIdx.x < 64) {
        float b = f32 ? ((const float*)dwc_b)[threadIdx.x]
                      : b2f(((const ushort*)dwc_b)[threadIdx.x]);
        wT[1600 + threadIdx.x] = b;
    }
}

// ---------- MFMA GEMM, dbuf DMA prefetch + XCD swizzle + LDS epilogue ----------
#define BM 128
#define BN 128
#define BK 32
__device__ __forceinline__ int swz(int r) { return (r ^ (r >> 2)) & 3; }

// smem layout (bytes): staging A0[0,8192) A1[8192,16384) B0[16384,24576)
// B1[24576,32768); epilogue fp32 half-tile 128 x 66 words overlaps from 0.
#define ELS_STRIDE 66

__global__ __launch_bounds__(256) void gemm_bt(
    const ushort* __restrict__ A, const ushort* __restrict__ Bt,
    int mode, const int* __restrict__ flag,
    const void* __restrict__ pos_enc, const void* __restrict__ bias,
    void* __restrict__ out0, ushort* __restrict__ out1, ushort* __restrict__ out2)
{
    __shared__ float smemf[8448];                  // 33792 B
    ushort* su = (ushort*)smemf;
    ushort* Abuf[2] = { su, su + 4096 };
    ushort* Bbuf[2] = { su + 8192, su + 12288 };

    bool f32 = flag[0] != 0;
    int tid  = threadIdx.x;

    // XCD swizzle: the nb n-blocks of one m-row land on the same XCD slot
    int nb  = gridDim.x;
    int fid = blockIdx.x + blockIdx.y * nb;
    int grp = fid / (8 * nb);
    int pos = fid % (8 * nb);
    int m0  = (grp * 8 + (pos & 7)) * BM;
    int n0  = (pos >> 3) * BN;

    int wave = tid >> 6, lane = tid & 63;
    int wm = wave & 1, wn = wave >> 1;
    int mrow = lane & 15, g = lane >> 4;

    // staging indices: instr t covers li = t*64+lane; row=li>>2, slot=li&3,
    // fetched global seg = slot ^ swz(row)
    int t0 = wave * 2;
    int li0 = t0 * 64 + lane, li1 = li0 + 64;
    int r0 = li0 >> 2, s0 = (li0 & 3) ^ swz(li0 >> 2);
    int r1 = li1 >> 2, s1 = (li1 & 3) ^ swz(li1 >> 2);
    const ushort* Ag0 = A + (size_t)(m0 + r0) * KDIM + s0 * 8;
    const ushort* Ag1 = A + (size_t)(m0 + r1) * KDIM + s1 * 8;
    const ushort* Bg0 = Bt + (size_t)(n0 + r0) * KDIM + s0 * 8;
    const ushort* Bg1 = Bt + (size_t)(n0 + r1) * KDIM + s1 * 8;

    floatx4 acc[4][4];
    #pragma unroll
    for (int i = 0; i < 4; i++)
        #pragma unroll
        for (int j = 0; j < 4; j++) acc[i][j] = (floatx4)0.f;

    // prefetch tile 0 into buffer 0
    async_copy16(&Abuf[0][t0 * 512], Ag0);
    async_copy16(&Abuf[0][(t0 + 1) * 512], Ag1);
    async_copy16(&Bbuf[0][t0 * 512], Bg0);
    async_copy16(&Bbuf[0][(t0 + 1) * 512], Bg1);
    __syncthreads();

    #pragma unroll
    for (int it = 0; it < 16; ++it) {
        int cur = it & 1;
        if (it < 15) {                       // prefetch next tile (overlaps compute)
            int nk = (it + 1) * BK;
            async_copy16(&Abuf[1 - cur][t0 * 512], Ag0 + nk);
            async_copy16(&Abuf[1 - cur][(t0 + 1) * 512], Ag1 + nk);
            async_copy16(&Bbuf[1 - cur][t0 * 512], Bg0 + nk);
            async_copy16(&Bbuf[1 - cur][(t0 + 1) * 512], Bg1 + nk);
        }
        bf16x8 af[4], bfr[4];
        #pragma unroll
        for (int i = 0; i < 4; i++) {
            int r = wm * 64 + i * 16 + mrow;
            af[i] = *(const bf16x8*)&Abuf[cur][r * 32 + (g ^ swz(r)) * 8];
        }
        #pragma unroll
        for (int i = 0; i < 4; i++) {
            int r = wn * 64 + i * 16 + mrow;
            bfr[i] = *(const bf16x8*)&Bbuf[cur][r * 32 + (g ^ swz(r)) * 8];
        }
        #pragma unroll
        for (int mi = 0; mi < 4; mi++)
            #pragma unroll
            for (int ni = 0; ni < 4; ni++)
                acc[mi][ni] = __builtin_amdgcn_mfma_f32_16x16x32_bf16(
                    af[mi], bfr[ni], acc[mi][ni], 0, 0, 0);
        __syncthreads();   // drains prefetch DMA (already overlapped) + guards bufs
    }

    // ---------- epilogue via LDS, two 64-col half-phases ----------
    // D mapping: col = lane&15, row = (lane>>4)*4 + reg (m89/m91-verified)
    int m_l = tid >> 1, seg = tid & 1;           // read-phase assignment
    int row = m0 + m_l;
    int b = row / NTOK;
    int n = row - b * NTOK;

    #pragma unroll
    for (int h = 0; h < 2; ++h) {
        __syncthreads();
        if (wn == h) {
            #pragma unroll
            for (int mi = 0; mi < 4; mi++) {
                int ml = wm * 64 + mi * 16 + g * 4;
                #pragma unroll
                for (int ni = 0; ni < 4; ni++)
                    #pragma unroll
                    for (int r = 0; r < 4; r++)
                        smemf[(ml + r) * ELS_STRIDE + ni * 16 + mrow] = acc[mi][ni][r];
            }
        }
        __syncthreads();
        // each thread: 32 floats of row m_l, cols [seg*32, seg*32+32)
        float v[32];
        #pragma unroll
        for (int j = 0; j < 32; j++) v[j] = smemf[m_l * ELS_STRIDE + seg * 32 + j];

        int colbase = n0 + h * 64 + seg * 32;    // global output column base
        if (mode == 1) {
            if (f32) {
                float* o = (float*)out0 + (size_t)row * 512 + colbase;
                #pragma unroll
                for (int j = 0; j < 32; j++) {
                    float bv = ((const float*)bias)[colbase + j];
                    o[j] = v[j] + bv;
                }
            } else {
                ushort* o = (ushort*)out0 + (size_t)row * 512 + colbase;
                #pragma unroll
                for (int j4 = 0; j4 < 4; j4++) {
                    ushort t[8];
                    #pragma unroll
                    for (int j = 0; j < 8; j++) {
                        float bv = b2f(((const ushort*)bias)[colbase + j4 * 8 + j]);
                        t[j] = f2b(v[j4 * 8 + j] + bv);
                    }
                    *(uint4*)(o + j4 * 8) = *(const uint4*)t;
                }
            }
        } else {
            if (n0 < 512) {                       // q: relu
                int head = colbase >> 6;
                int e0 = colbase & 63;
                ushort* o = (ushort*)out0 + (((size_t)b * 8 + head) * NTOK + n) * 64 + e0;
                #pragma unroll
                for (int j4 = 0; j4 < 4; j4++) {
                    ushort t[8];
                    #pragma unroll
                    for (int j = 0; j < 8; j++) t[j] = f2b(fmaxf(v[j4 * 8 + j], 0.f));
                    *(uint4*)(o + j4 * 8) = *(const uint4*)t;
                }
            } else if (n0 < 1024) {               // k: + pos_enc, relu
                int d0 = colbase - 512;
                int head = d0 >> 6;
                int e0 = d0 & 63;
                ushort* o = out1 + (((size_t)b * 8 + head) * NTOK + n) * 64 + e0;
                #pragma unroll
                for (int j4 = 0; j4 < 4; j4++) {
                    ushort t[8];
                    #pragma unroll
                    for (int j = 0; j < 8; j++) {
                        float pe = f32 ? ((const float*)pos_enc)[(size_t)n * 512 + d0 + j4 * 8 + j]
                                       : b2f(((const ushort*)pos_enc)[(size_t)n * 512 + d0 + j4 * 8 + j]);
                        t[j] = f2b(fmaxf(v[j4 * 8 + j] + pe, 0.f));
                    }
                    *(uint4*)(o + j4 * 8) = *(const uint4*)t;
                }
            } else {                              // v: copy
                int d0 = colbase - 1024;
                int head = d0 >> 6;
                int e0 = d0 & 63;
                ushort* o = out2 + (((size_t)b * 8 + head) * NTOK + n) * 64 + e0;
                #pragma unroll
                for (int j4 = 0; j4 < 4; j4++) {
                    ushort t[8];
                    #pragma unroll
                    for (int j = 0; j < 8; j++) t[j] = f2b(v[j4 * 8 + j]);
                    *(uint4*)(o + j4 * 8) = *(const uint4*)t;
                }
            }
        }
    }
}

// ---------- ctx[d][e] = sum_n k[n][d] v[n][e] + k_sum, atomic ----------
#define SPLITS 7
#define NPER   (NTOK / SPLITS)   // 448

__global__ __launch_bounds__(256) void ctx_ksum(
    const ushort* __restrict__ kbuf, const ushort* __restrict__ vbuf,
    float* __restrict__ ctx, float* __restrict__ ksum)
{
    int bh = blockIdx.x, sp = blockIdx.y;
    int nstart = sp * NPER;
    __shared__ float kls[64 * 64];
    __shared__ float vls[64 * 64];
    int tid  = threadIdx.x;
    int lane = tid & 63;
    int wave = tid >> 6;
    float acc[16];
    #pragma unroll
    for (int i = 0; i < 16; i++) acc[i] = 0.f;
    float ks = 0.f;
    size_t base = ((size_t)bh * NTOK + nstart) * 64;

    for (int nc = 0; nc < NPER; nc += 64) {
        for (int c = tid; c < 512; c += 256) {
            uint4 ku = *(const uint4*)(kbuf + base + (size_t)nc * 64 + c * 8);
            uint4 vu = *(const uint4*)(vbuf + base + (size_t)nc * 64 + c * 8);
            const ushort* kp = (const ushort*)&ku;
            const ushort* vp = (const ushort*)&vu;
            #pragma unroll
            for (int j = 0; j < 8; j++) {
                kls[c * 8 + j] = b2f(kp[j]);
                vls[c * 8 + j] = b2f(vp[j]);
            }
        }
        __syncthreads();
        for (int nl = 0; nl < 64; ++nl) {
            float kd = kls[nl * 64 + lane];
            if (wave == 0) ks += kd;
            const float* vp = &vls[nl * 64 + wave * 16];
            #pragma unroll
            for (int i = 0; i < 16; i++) acc[i] += kd * vp[i];
        }
        __syncthreads();
    }
    float* cp = ctx + (size_t)bh * 4096 + lane * 64 + wave * 16;
    #pragma unroll
    for (int i = 0; i < 16; i++) atomicAdd(&cp[i], acc[i]);
    if (wave == 0) atomicAdd(&ksum[(size_t)bh * 64 + lane], ks);
}

// ---------- attn = (q @ ctx) * d_inv -> ybuf ----------
__global__ __launch_bounds__(256) void attn_kernel(
    const ushort* __restrict__ q, const float* __restrict__ ctx,
    const float* __restrict__ ksum, ushort* __restrict__ ybuf)
{
    int bx = blockIdx.x;
    int bh = bx / 49, chunk = bx % 49;
    int n0 = chunk * 64;
    __shared__ float ctxs[4096];
    __shared__ float ksums[64];
    __shared__ float dinv[64];
    int tid = threadIdx.x;
    for (int i = tid; i < 4096; i += 256) ctxs[i] = ctx[(size_t)bh * 4096 + i];
    if (tid < 64) ksums[tid] = ksum[(size_t)bh * 64 + tid];
    __syncthreads();
    int nl = tid & 63, wave = tid >> 6;
    size_t qbase = ((size_t)bh * NTOK + n0 + nl) * 64;
    float qr[64];
    #pragma unroll
    for (int i = 0; i < 8; i++) {
        uint4 u = *(const uint4*)(q + qbase + i * 8);
        const ushort* p = (const ushort*)&u;
        #pragma unroll
        for (int j = 0; j < 8; j++) qr[i * 8 + j] = b2f(p[j]);
    }
    if (wave == 0) {
        float s = 0.f;
        #pragma unroll
        for (int d = 0; d < 64; ++d) s += qr[d] * ksums[d];
        dinv[nl] = 1.0f / (s + 1e-6f);
    }
    __syncthreads();
    float acc[16];
    #pragma unroll
    for (int i = 0; i < 16; i++) acc[i] = 0.f;
    for (int d = 0; d < 64; ++d) {
        float qd = qr[d];
        const float* c = &ctxs[d * 64 + wave * 16];
        #pragma unroll
        for (int i = 0; i < 16; i++) acc[i] += qd * c[i];
    }
    float di = dinv[nl];
    size_t obase = qbase + wave * 16;
    #pragma unroll
    for (int i = 0; i < 16; i++) ybuf[obase + i] = f2b(acc[i] * di);
}

// ---------- y += depthwise 5x5 conv(v) + bias ----------
__global__ __launch_bounds__(256) void dwc_add(
    const ushort* __restrict__ v, const float* __restrict__ wT,
    ushort* __restrict__ ybuf)
{
    __shared__ float wls[1664];
    for (int i = threadIdx.x; i < 1664; i += 256) wls[i] = wT[i];
    __syncthreads();

    int t = blockIdx.x * 256 + threadIdx.x;
    int eg = (t & 7) * 8;
    int r = t >> 3;
    int n  = r % NTOK;
    int bh = r / NTOK;
    int y = n / HSP, x = n % HSP;

    float acc[8];
    #pragma unroll
    for (int j = 0; j < 8; j++) acc[j] = wls[1600 + eg + j];

    const ushort* vb = v + (size_t)bh * NTOK * 64 + eg;
    #pragma unroll
    for (int dy = 0; dy < 5; ++dy) {
        int yy = y + dy - 2;
        if (yy < 0 || yy >= HSP) continue;
        #pragma unroll
        for (int dx = 0; dx < 5; ++dx) {
            int xx = x + dx - 2;
            if (xx < 0 || xx >= HSP) continue;
            uint4 u = *(const uint4*)(vb + (size_t)(yy * HSP + xx) * 64);
            const ushort* up = (const ushort*)&u;
            const float* wp = &wls[(dy * 5 + dx) * 64 + eg];
            #pragma unroll
            for (int j = 0; j < 8; j++) acc[j] += wp[j] * b2f(up[j]);
        }
    }
    size_t o = (size_t)r * 64 + eg;
    uint4 yo = *(const uint4*)(ybuf + o);
    const ushort* yp = (const ushort*)&yo;
    ushort res[8];
    #pragma unroll
    for (int j = 0; j < 8; j++) res[j] = f2b(acc[j] + b2f(yp[j]));
    *(uint4*)(ybuf + o) = *(const uint4*)res;
}

// ---------- launch ----------
extern "C" void kernel_launch(void* const* d_in, const int* in_sizes, int n_in,
                              void* d_out, int out_size, void* d_ws, size_t ws_size,
                              hipStream_t stream) {
    const void* x    = d_in[0];
    const void* Wq   = d_in[1];
    const void* Wkv  = d_in[2];
    const void* pos  = d_in[3];
    const void* dwcw = d_in[4];
    const void* dwcb = d_in[5];
    const void* Wp   = d_in[6];
    const void* bp   = d_in[7];

    char* ws = (char*)d_ws;
    const size_t SZ_BIG = 51380224;                    // 50176*512*2
    int*    flag   = (int*)(ws + 0);
    ushort* WqkvT  = (ushort*)(ws + 4096);
    ushort* WpT    = (ushort*)(ws + 4096 + 1572864);
    float*  wTdwc  = (float*)(ws + 2101248);
    float*  ctx    = (float*)(ws + 2107904);
    float*  ksum   = (float*)(ws + 4205056);
    ushort* qbuf   = (ushort*)(ws + 4237824);
    ushort* kbuf   = (ushort*)(ws + 4237824 + SZ_BIG);     // reused as y
    ushort* vbuf   = (ushort*)(ws + 4237824 + 2 * SZ_BIG);
    ushort* xbf = (ushort*)d_out;   // dead until gemm2's final write

    detect_dtype<<<1, 256, 0, stream>>>((const ushort*)x, flag);
    hipMemsetAsync(ctx, 0, 2097152 + 32768, stream);

    prep_weights<<<4096, 256, 0, stream>>>(Wq, Wkv, Wp, flag, WqkvT, WpT);
    prep_dwc<<<1, 256, 0, stream>>>(dwcw, dwcb, flag, wTdwc);
    convert_x<<<12544, 256, 0, stream>>>(x, flag, xbf);

    gemm_bt<<<dim3(1536 / BN, MROWS / BM), 256, 0, stream>>>(
        xbf, WqkvT, 0, flag, pos, nullptr, qbuf, kbuf, vbuf);

    ctx_ksum<<<dim3(128, SPLITS), 256, 0, stream>>>(kbuf, vbuf, ctx, ksum);

    attn_kernel<<<128 * 49, 256, 0, stream>>>(qbuf, ctx, ksum, kbuf);

    dwc_add<<<12544, 256, 0, stream>>>(vbuf, wTdwc, kbuf);

    gemm_bt<<<dim3(512 / BN, MROWS / BM), 256, 0, stream>>>(
        kbuf, WpT, 1, flag, nullptr, bp, d_out, nullptr, nullptr);
}

// Round 7
// 573.404 us; speedup vs baseline: 2.8755x; 1.4603x over previous
//
#include <hip/hip_runtime.h>

// ---------- bf16 helpers (raw ushort representation) ----------
__device__ __forceinline__ float b2f(ushort u) {
    union { float f; unsigned int i; } w; w.i = ((unsigned int)u) << 16; return w.f;
}
__device__ __forceinline__ ushort f2b(float f) {
    union { float f; unsigned int i; } w; w.f = f;
    unsigned int lsb = (w.i >> 16) & 1u;
    w.i += 0x7fffu + lsb;
    return (ushort)(w.i >> 16);
}

typedef __bf16 bf16x8 __attribute__((ext_vector_type(8)));
typedef float floatx4 __attribute__((ext_vector_type(4)));

// async global->LDS, 16B per lane; lane i lands at lds_base + i*16B (HW rule)
__device__ __forceinline__ void async_copy16(ushort* lds_base, const ushort* gptr) {
    __builtin_amdgcn_global_load_lds(
        (const __attribute__((address_space(1))) unsigned int*)gptr,
        (__attribute__((address_space(3))) unsigned int*)lds_base,
        16, 0, 0);
}

// Problem constants
#define BATCH 16
#define NTOK  3136
#define NHEAD 8
#define HDIM  64
#define HSP   56
#define MROWS (BATCH * NTOK)   // 50176
#define KDIM  512              // both GEMMs have K = 512

// ---------- dtype detection ----------
__global__ __launch_bounds__(256) void detect_dtype(const ushort* __restrict__ x,
                                                    int* __restrict__ flag)
{
    __shared__ int s;
    if (threadIdx.x == 0) s = 0;
    __syncthreads();
    int bad = 0;
    for (int i = threadIdx.x; i < 4096; i += 256) {
        int e = (x[i] >> 7) & 0xFF;
        if (e >= 0x90) bad = 1;
    }
    if (bad) s = 1;
    __syncthreads();
    if (threadIdx.x == 0) flag[0] = s;   // 1 => inputs are fp32
}

// ---------- convert x -> bf16 ----------
__global__ __launch_bounds__(256) void convert_x(
    const void* __restrict__ x, const int* __restrict__ flag,
    ushort* __restrict__ xbf)
{
    size_t t = (size_t)blockIdx.x * 256 + threadIdx.x;
    if (flag[0]) {
        const float* xf = (const float*)x + t * 8;
        float4 f0 = *(const float4*)xf;
        float4 f1 = *(const float4*)(xf + 4);
        ushort o[8] = { f2b(f0.x), f2b(f0.y), f2b(f0.z), f2b(f0.w),
                        f2b(f1.x), f2b(f1.y), f2b(f1.z), f2b(f1.w) };
        *(uint4*)(xbf + t * 8) = *(const uint4*)o;
    } else {
        *(uint4*)(xbf + t * 8) = *((const uint4*)x + t);
    }
}

// ---------- weight transpose ----------
__global__ __launch_bounds__(256) void prep_weights(
    const void* __restrict__ Wq, const void* __restrict__ Wkv,
    const void* __restrict__ Wp, const int* __restrict__ flag,
    ushort* __restrict__ WqkvT, ushort* __restrict__ WpT)
{
    bool f32 = flag[0] != 0;
    int idx = blockIdx.x * 256 + threadIdx.x;
    int kk = idx & 511;
    int n  = idx >> 9;
    if (n < 1536) {
        ushort val;
        if (n < 512)
            val = f32 ? f2b(((const float*)Wq)[kk * 512 + n])
                      : ((const ushort*)Wq)[kk * 512 + n];
        else
            val = f32 ? f2b(((const float*)Wkv)[kk * 1024 + (n - 512)])
                      : ((const ushort*)Wkv)[kk * 1024 + (n - 512)];
        WqkvT[n * 512 + kk] = val;
    } else {
        int n2 = n - 1536;
        WpT[n2 * 512 + kk] = f32 ? f2b(((const float*)Wp)[kk * 512 + n2])
                                 : ((const ushort*)Wp)[kk * 512 + n2];
    }
}

// ---------- prep dwc weights ----------
__global__ __launch_bounds__(256) void prep_dwc(
    const void* __restrict__ dwc_w, const void* __restrict__ dwc_b,
    const int* __restrict__ flag, float* __restrict__ wT)
{
    bool f32 = flag[0] != 0;
    for (int i = threadIdx.x; i < 1600; i += 256) {
        int e = i / 25, tap = i % 25;
        float w = f32 ? ((const float*)dwc_w)[i] : b2f(((const ushort*)dwc_w)[i]);
        wT[tap * 64 + e] = w;
    }
    if (threadIdx.x < 64) {
        float b = f32 ? ((const float*)dwc_b)[threadIdx.x]
                      : b2f(((const ushort*)dwc_b)[threadIdx.x]);
        wT[1600 + threadIdx.x] = b;
    }
}

// ---------- MFMA GEMM, dbuf DMA prefetch + XCD swizzle + LDS epilogue ----------
#define BM 128
#define BN 128
#define BK 32
__device__ __forceinline__ int swz(int r) { return (r ^ (r >> 2)) & 3; }

#define ELS_STRIDE 66

__global__ __launch_bounds__(256) void gemm_bt(
    const ushort* __restrict__ A, const ushort* __restrict__ Bt,
    int mode, const int* __restrict__ flag,
    const void* __restrict__ pos_enc, const void* __restrict__ bias,
    void* __restrict__ out0, ushort* __restrict__ out1, ushort* __restrict__ out2)
{
    __shared__ float smemf[8448];                  // 33792 B
    ushort* su = (ushort*)smemf;
    ushort* Abuf[2] = { su, su + 4096 };
    ushort* Bbuf[2] = { su + 8192, su + 12288 };

    bool f32 = flag[0] != 0;
    int tid  = threadIdx.x;

    int nb  = gridDim.x;
    int fid = blockIdx.x + blockIdx.y * nb;
    int grp = fid / (8 * nb);
    int pos = fid % (8 * nb);
    int m0  = (grp * 8 + (pos & 7)) * BM;
    int n0  = (pos >> 3) * BN;

    int wave = tid >> 6, lane = tid & 63;
    int wm = wave & 1, wn = wave >> 1;
    int mrow = lane & 15, g = lane >> 4;

    int t0 = wave * 2;
    int li0 = t0 * 64 + lane, li1 = li0 + 64;
    int r0 = li0 >> 2, s0 = (li0 & 3) ^ swz(li0 >> 2);
    int r1 = li1 >> 2, s1 = (li1 & 3) ^ swz(li1 >> 2);
    const ushort* Ag0 = A + (size_t)(m0 + r0) * KDIM + s0 * 8;
    const ushort* Ag1 = A + (size_t)(m0 + r1) * KDIM + s1 * 8;
    const ushort* Bg0 = Bt + (size_t)(n0 + r0) * KDIM + s0 * 8;
    const ushort* Bg1 = Bt + (size_t)(n0 + r1) * KDIM + s1 * 8;

    floatx4 acc[4][4];
    #pragma unroll
    for (int i = 0; i < 4; i++)
        #pragma unroll
        for (int j = 0; j < 4; j++) acc[i][j] = (floatx4)0.f;

    async_copy16(&Abuf[0][t0 * 512], Ag0);
    async_copy16(&Abuf[0][(t0 + 1) * 512], Ag1);
    async_copy16(&Bbuf[0][t0 * 512], Bg0);
    async_copy16(&Bbuf[0][(t0 + 1) * 512], Bg1);
    __syncthreads();

    #pragma unroll
    for (int it = 0; it < 16; ++it) {
        int cur = it & 1;
        if (it < 15) {
            int nk = (it + 1) * BK;
            async_copy16(&Abuf[1 - cur][t0 * 512], Ag0 + nk);
            async_copy16(&Abuf[1 - cur][(t0 + 1) * 512], Ag1 + nk);
            async_copy16(&Bbuf[1 - cur][t0 * 512], Bg0 + nk);
            async_copy16(&Bbuf[1 - cur][(t0 + 1) * 512], Bg1 + nk);
        }
        bf16x8 af[4], bfr[4];
        #pragma unroll
        for (int i = 0; i < 4; i++) {
            int r = wm * 64 + i * 16 + mrow;
            af[i] = *(const bf16x8*)&Abuf[cur][r * 32 + (g ^ swz(r)) * 8];
        }
        #pragma unroll
        for (int i = 0; i < 4; i++) {
            int r = wn * 64 + i * 16 + mrow;
            bfr[i] = *(const bf16x8*)&Bbuf[cur][r * 32 + (g ^ swz(r)) * 8];
        }
        #pragma unroll
        for (int mi = 0; mi < 4; mi++)
            #pragma unroll
            for (int ni = 0; ni < 4; ni++)
                acc[mi][ni] = __builtin_amdgcn_mfma_f32_16x16x32_bf16(
                    af[mi], bfr[ni], acc[mi][ni], 0, 0, 0);
        __syncthreads();
    }

    int m_l = tid >> 1, seg = tid & 1;
    int row = m0 + m_l;
    int b = row / NTOK;
    int n = row - b * NTOK;

    #pragma unroll
    for (int h = 0; h < 2; ++h) {
        __syncthreads();
        if (wn == h) {
            #pragma unroll
            for (int mi = 0; mi < 4; mi++) {
                int ml = wm * 64 + mi * 16 + g * 4;
                #pragma unroll
                for (int ni = 0; ni < 4; ni++)
                    #pragma unroll
                    for (int r = 0; r < 4; r++)
                        smemf[(ml + r) * ELS_STRIDE + ni * 16 + mrow] = acc[mi][ni][r];
            }
        }
        __syncthreads();
        float v[32];
        #pragma unroll
        for (int j = 0; j < 32; j++) v[j] = smemf[m_l * ELS_STRIDE + seg * 32 + j];

        int colbase = n0 + h * 64 + seg * 32;
        if (mode == 1) {
            if (f32) {
                float* o = (float*)out0 + (size_t)row * 512 + colbase;
                #pragma unroll
                for (int j = 0; j < 32; j++) {
                    float bv = ((const float*)bias)[colbase + j];
                    o[j] = v[j] + bv;
                }
            } else {
                ushort* o = (ushort*)out0 + (size_t)row * 512 + colbase;
                #pragma unroll
                for (int j4 = 0; j4 < 4; j4++) {
                    ushort t[8];
                    #pragma unroll
                    for (int j = 0; j < 8; j++) {
                        float bv = b2f(((const ushort*)bias)[colbase + j4 * 8 + j]);
                        t[j] = f2b(v[j4 * 8 + j] + bv);
                    }
                    *(uint4*)(o + j4 * 8) = *(const uint4*)t;
                }
            }
        } else {
            if (n0 < 512) {
                int head = colbase >> 6;
                int e0 = colbase & 63;
                ushort* o = (ushort*)out0 + (((size_t)b * 8 + head) * NTOK + n) * 64 + e0;
                #pragma unroll
                for (int j4 = 0; j4 < 4; j4++) {
                    ushort t[8];
                    #pragma unroll
                    for (int j = 0; j < 8; j++) t[j] = f2b(fmaxf(v[j4 * 8 + j], 0.f));
                    *(uint4*)(o + j4 * 8) = *(const uint4*)t;
                }
            } else if (n0 < 1024) {
                int d0 = colbase - 512;
                int head = d0 >> 6;
                int e0 = d0 & 63;
                ushort* o = out1 + (((size_t)b * 8 + head) * NTOK + n) * 64 + e0;
                #pragma unroll
                for (int j4 = 0; j4 < 4; j4++) {
                    ushort t[8];
                    #pragma unroll
                    for (int j = 0; j < 8; j++) {
                        float pe = f32 ? ((const float*)pos_enc)[(size_t)n * 512 + d0 + j4 * 8 + j]
                                       : b2f(((const ushort*)pos_enc)[(size_t)n * 512 + d0 + j4 * 8 + j]);
                        t[j] = f2b(fmaxf(v[j4 * 8 + j] + pe, 0.f));
                    }
                    *(uint4*)(o + j4 * 8) = *(const uint4*)t;
                }
            } else {
                int d0 = colbase - 1024;
                int head = d0 >> 6;
                int e0 = d0 & 63;
                ushort* o = out2 + (((size_t)b * 8 + head) * NTOK + n) * 64 + e0;
                #pragma unroll
                for (int j4 = 0; j4 < 4; j4++) {
                    ushort t[8];
                    #pragma unroll
                    for (int j = 0; j < 8; j++) t[j] = f2b(v[j4 * 8 + j]);
                    *(uint4*)(o + j4 * 8) = *(const uint4*)t;
                }
            }
        }
    }
}

// ---------- ctx = k^T v via MFMA (+ fused ksum), atomic fp32 accumulation ----------
// Per (bh, split): stage k,v tiles transposed to [64][32] bf16 in LDS, then
// wave w computes d-tile w x all 4 e-tiles: ctx[d][e] += sum_n k[n][d] v[n][e].
#define SPLITS 7
#define NPER   (NTOK / SPLITS)   // 448 = 14 * 32

__global__ __launch_bounds__(256) void ctx_ksum(
    const ushort* __restrict__ kbuf, const ushort* __restrict__ vbuf,
    float* __restrict__ ctx, float* __restrict__ ksum)
{
    __shared__ ushort kT[64 * 32];    // [d][n] bf16, XOR-block swizzled
    __shared__ ushort vT[64 * 32];    // [e][n] bf16, XOR-block swizzled
    __shared__ float ks4[256];
    int bh = blockIdx.x, sp = blockIdx.y;
    int tid = threadIdx.x;
    int lane = tid & 63, wave = tid >> 6;
    int mrow = lane & 15, g = lane >> 4;
    int r = tid & 31, cblk = tid >> 5;       // staging: n-row r, d/e-octet cblk
    size_t base = ((size_t)bh * NTOK + sp * NPER) * 64;

    floatx4 acc[4];
    #pragma unroll
    for (int c = 0; c < 4; c++) acc[c] = (floatx4)0.f;
    float kpart = 0.f;
    int kd = tid >> 2, kq = tid & 3;         // ksum: d, physical quarter (order-invariant)

    for (int nc = 0; nc < NPER; nc += 32) {
        uint4 ku = *(const uint4*)(kbuf + base + (size_t)(nc + r) * 64 + cblk * 8);
        uint4 vu = *(const uint4*)(vbuf + base + (size_t)(nc + r) * 64 + cblk * 8);
        __syncthreads();                     // previous tile fully consumed
        const ushort* kp = (const ushort*)&ku;
        const ushort* vp = (const ushort*)&vu;
        #pragma unroll
        for (int j = 0; j < 8; j++) {
            int d = cblk * 8 + j;
            int blk = (r >> 3) ^ swz(d);
            kT[d * 32 + blk * 8 + (r & 7)] = kp[j];
            vT[d * 32 + blk * 8 + (r & 7)] = vp[j];
        }
        __syncthreads();
        // ksum partial from staged tile (any quarter order sums the same)
        {
            const ushort* p = &kT[kd * 32 + kq * 8];
            #pragma unroll
            for (int j = 0; j < 8; j++) kpart += b2f(p[j]);
        }
        // MFMA: A-frag m=d (row wave*16+mrow), k=n (block g); B-frag col=e, k=n
        int dr = wave * 16 + mrow;
        bf16x8 af = *(const bf16x8*)&kT[dr * 32 + (g ^ swz(dr)) * 8];
        #pragma unroll
        for (int c = 0; c < 4; c++) {
            int er = c * 16 + mrow;
            bf16x8 bf = *(const bf16x8*)&vT[er * 32 + (g ^ swz(er)) * 8];
            acc[c] = __builtin_amdgcn_mfma_f32_16x16x32_bf16(af, bf, acc[c], 0, 0, 0);
        }
    }
    // D: row (d-offset) = g*4+rr, col (e-offset) = mrow
    #pragma unroll
    for (int c = 0; c < 4; c++)
        #pragma unroll
        for (int rr = 0; rr < 4; rr++) {
            int d = wave * 16 + g * 4 + rr;
            int e = c * 16 + mrow;
            atomicAdd(&ctx[bh * 4096 + d * 64 + e], acc[c][rr]);
        }
    ks4[tid] = kpart;
    __syncthreads();
    if (tid < 64) {
        float s = ks4[tid * 4] + ks4[tid * 4 + 1] + ks4[tid * 4 + 2] + ks4[tid * 4 + 3];
        atomicAdd(&ksum[bh * 64 + tid], s);
    }
}

// ---------- attn = (q @ ctx) * d_inv via MFMA -> ybuf ----------
// ctx augmented with ksum as column 64: MFMA col 64 yields q.ksum per token,
// so d_inv comes out of the same matmul (no second q pass).
__global__ __launch_bounds__(256) void attn_kernel(
    const ushort* __restrict__ q, const float* __restrict__ ctx,
    const float* __restrict__ ksum, ushort* __restrict__ ybuf)
{
    __shared__ float smem[4352];             // 17408 B; ctxT (10240 B) aliases sout
    ushort* ctxT = (ushort*)smem;            // [80 e][64 d] bf16, 8-block swizzle
    float* sout = smem;                      // [64][68] fp32 epilogue
    int bh = blockIdx.x, cg = blockIdx.y;
    int tid = threadIdx.x;
    int lane = tid & 63, wave = tid >> 6;
    int mrow = lane & 15, g = lane >> 4;

    for (int i = tid; i < 640; i += 256) {
        int e = i >> 3, blk = i & 7;
        ushort tmp[8];
        #pragma unroll
        for (int j = 0; j < 8; j++) {
            int d = blk * 8 + j;
            float v = 0.f;
            if (e < 64) v = ctx[bh * 4096 + d * 64 + e];
            else if (e == 64) v = ksum[bh * 64 + d];
            tmp[j] = f2b(v);
        }
        *(uint4*)&ctxT[e * 64 + (blk ^ (e & 7)) * 8] = *(const uint4*)tmp;
    }
    __syncthreads();

    // hoist all B-frags (loop-invariant across token chunks)
    bf16x8 bfr[2][5];
    #pragma unroll
    for (int kt = 0; kt < 2; kt++)
        #pragma unroll
        for (int c = 0; c < 5; c++) {
            int e = c * 16 + mrow;
            bfr[kt][c] = *(const bf16x8*)&ctxT[e * 64 + ((kt * 4 + g) ^ (e & 7)) * 8];
        }

    int token4 = tid >> 2, seg = tid & 3;
    for (int cc = 0; cc < 7; cc++) {
        int n0 = (cg * 7 + cc) * 64;
        floatx4 acc[5];
        #pragma unroll
        for (int c = 0; c < 5; c++) acc[c] = (floatx4)0.f;
        size_t qrow = ((size_t)bh * NTOK + n0 + wave * 16 + mrow) * 64;
        #pragma unroll
        for (int kt = 0; kt < 2; kt++) {
            bf16x8 af = *(const bf16x8*)(q + qrow + kt * 32 + g * 8);
            #pragma unroll
            for (int c = 0; c < 5; c++)
                acc[c] = __builtin_amdgcn_mfma_f32_16x16x32_bf16(af, bfr[kt][c], acc[c], 0, 0, 0);
        }
        __syncthreads();                     // prev sout readers done (cc=0: ctxT preload done)
        #pragma unroll
        for (int c = 0; c < 4; c++)
            #pragma unroll
            for (int rr = 0; rr < 4; rr++)
                sout[(wave * 16 + g * 4 + rr) * 68 + c * 16 + mrow] = acc[c][rr];
        if (mrow == 0) {
            #pragma unroll
            for (int rr = 0; rr < 4; rr++)
                sout[(wave * 16 + g * 4 + rr) * 68 + 64] = acc[4][rr];
        }
        __syncthreads();
        float dinv = 1.0f / (sout[token4 * 68 + 64] + 1e-6f);
        const float* sp = &sout[token4 * 68 + seg * 16];
        ushort res[16];
        #pragma unroll
        for (int j = 0; j < 16; j++) res[j] = f2b(sp[j] * dinv);
        ushort* o = ybuf + ((size_t)bh * NTOK + n0 + token4) * 64 + seg * 16;
        *(uint4*)o = *(const uint4*)res;
        *(uint4*)(o + 8) = *(const uint4*)(res + 8);
    }
}

// ---------- y += depthwise 5x5 conv(v) + bias ----------
__global__ __launch_bounds__(256) void dwc_add(
    const ushort* __restrict__ v, const float* __restrict__ wT,
    ushort* __restrict__ ybuf)
{
    __shared__ float wls[1664];
    for (int i = threadIdx.x; i < 1664; i += 256) wls[i] = wT[i];
    __syncthreads();

    int t = blockIdx.x * 256 + threadIdx.x;
    int eg = (t & 7) * 8;
    int r = t >> 3;
    int n  = r % NTOK;
    int bh = r / NTOK;
    int y = n / HSP, x = n % HSP;

    float acc[8];
    #pragma unroll
    for (int j = 0; j < 8; j++) acc[j] = wls[1600 + eg + j];

    const ushort* vb = v + (size_t)bh * NTOK * 64 + eg;
    #pragma unroll
    for (int dy = 0; dy < 5; ++dy) {
        int yy = y + dy - 2;
        if (yy < 0 || yy >= HSP) continue;
        #pragma unroll
        for (int dx = 0; dx < 5; ++dx) {
            int xx = x + dx - 2;
            if (xx < 0 || xx >= HSP) continue;
            uint4 u = *(const uint4*)(vb + (size_t)(yy * HSP + xx) * 64);
            const ushort* up = (const ushort*)&u;
            const float* wp = &wls[(dy * 5 + dx) * 64 + eg];
            #pragma unroll
            for (int j = 0; j < 8; j++) acc[j] += wp[j] * b2f(up[j]);
        }
    }
    size_t o = (size_t)r * 64 + eg;
    uint4 yo = *(const uint4*)(ybuf + o);
    const ushort* yp = (const ushort*)&yo;
    ushort res[8];
    #pragma unroll
    for (int j = 0; j < 8; j++) res[j] = f2b(acc[j] + b2f(yp[j]));
    *(uint4*)(ybuf + o) = *(const uint4*)res;
}

// ---------- launch ----------
extern "C" void kernel_launch(void* const* d_in, const int* in_sizes, int n_in,
                              void* d_out, int out_size, void* d_ws, size_t ws_size,
                              hipStream_t stream) {
    const void* x    = d_in[0];
    const void* Wq   = d_in[1];
    const void* Wkv  = d_in[2];
    const void* pos  = d_in[3];
    const void* dwcw = d_in[4];
    const void* dwcb = d_in[5];
    const void* Wp   = d_in[6];
    const void* bp   = d_in[7];

    char* ws = (char*)d_ws;
    const size_t SZ_BIG = 51380224;                    // 50176*512*2
    int*    flag   = (int*)(ws + 0);
    ushort* WqkvT  = (ushort*)(ws + 4096);
    ushort* WpT    = (ushort*)(ws + 4096 + 1572864);
    float*  wTdwc  = (float*)(ws + 2101248);
    float*  ctx    = (float*)(ws + 2107904);
    float*  ksum   = (float*)(ws + 4205056);
    ushort* qbuf   = (ushort*)(ws + 4237824);
    ushort* kbuf   = (ushort*)(ws + 4237824 + SZ_BIG);     // reused as y
    ushort* vbuf   = (ushort*)(ws + 4237824 + 2 * SZ_BIG);
    ushort* xbf = (ushort*)d_out;   // dead until gemm2's final write

    detect_dtype<<<1, 256, 0, stream>>>((const ushort*)x, flag);
    hipMemsetAsync(ctx, 0, 2097152 + 32768, stream);

    prep_weights<<<4096, 256, 0, stream>>>(Wq, Wkv, Wp, flag, WqkvT, WpT);
    prep_dwc<<<1, 256, 0, stream>>>(dwcw, dwcb, flag, wTdwc);
    convert_x<<<12544, 256, 0, stream>>>(x, flag, xbf);

    gemm_bt<<<dim3(1536 / BN, MROWS / BM), 256, 0, stream>>>(
        xbf, WqkvT, 0, flag, pos, nullptr, qbuf, kbuf, vbuf);

    ctx_ksum<<<dim3(128, SPLITS), 256, 0, stream>>>(kbuf, vbuf, ctx, ksum);

    attn_kernel<<<dim3(128, 7), 256, 0, stream>>>(qbuf, ctx, ksum, kbuf);

    dwc_add<<<12544, 256, 0, stream>>>(vbuf, wTdwc, kbuf);

    gemm_bt<<<dim3(512 / BN, MROWS / BM), 256, 0, stream>>>(
        kbuf, WpT, 1, flag, nullptr, bp, d_out, nullptr, nullptr);
}